// Round 8
// baseline (299.180 us; speedup 1.0000x reference)
//
#include <hip/hip_runtime.h>
#include <hip/hip_bf16.h>

// Problem dims
#define NTOK 8192       // B*T
#define NASN 16384      // NTOK * K(=2)
#define C_ 512
#define H_ 2048
#define E_ 8
#define RBC 2048        // router blocks (4 tokens each) = count granularity

typedef __bf16 bf16x8 __attribute__((ext_vector_type(8)));
typedef float f32x4 __attribute__((ext_vector_type(4)));

// Workspace layout (bytes). Total ~109.5 MB.
#define WS_COUNTS 0                              // RBC*8*4 = 64 KB (written, not atomically)
#define WS_OFFS   65536                          // 9*4 -> pad 256
#define WS_T1S    65792                          // 9*4
#define WS_QC     65856                          // 2*4 dynamic-tile-queue counters
#define WS_INFO   66048                          // NTOK*16
#define WS_TOKL   (WS_INFO + NTOK*16)            // NASN*4
#define WS_SLOTS  (WS_TOKL + NASN*4)             // NTOK*8 (int2)
#define WS_XBF    (WS_SLOTS + NTOK*8)            // NTOK*C_*2 bf16 token-ordered x
#define WS_W1B    (WS_XBF + (size_t)NTOK*C_*2)   // E*H*C bf16, [e][h][c]
#define WS_W2B    (WS_W1B + (size_t)E_*H_*C_*2)  // E*C*H bf16, [e][c][h]
#define WS_HS     (WS_W2B + (size_t)E_*H_*C_*2)  // NASN*H bf16 hidden acts
// Ys (bf16, NASN*C_*2 = 16.78 MB) aliases Xbf+W1b (25.2 MB, dead by k_gemm2).
#define WS_YS     WS_XBF

__device__ __forceinline__ unsigned int f2bf(float f) {
  __hip_bfloat16 h = __float2bfloat16(f);
  return (unsigned int)*(unsigned short*)&h;
}
__device__ __forceinline__ float bf2f(unsigned int u) {
  return __int_as_float((u & 0xffffu) << 16);
}

// async global->LDS, 16B per lane; LDS dest = wave-uniform base + lane*16
__device__ __forceinline__ void g2l16(const unsigned short* g, unsigned short* l) {
  __builtin_amdgcn_global_load_lds(
      (const __attribute__((address_space(1))) unsigned int*)g,
      (__attribute__((address_space(3))) unsigned int*)l, 16, 0, 0);
}

// Pair-interleaved XOR LDS layout for a [rows x 32 ushort] panel:
// 16B chunk of (row r, k-chunk q) at linear chunk (r>>1)*8 + slot,
// slot = ((r&1)*4 + q) ^ ((r>>1)&7).  Full 32-bank coverage on fragment reads.
__device__ __forceinline__ void stage_decode(int L, int& brow, int& q) {
  int s = L >> 3, slot = L & 7;
  int v = slot ^ (s & 7);
  brow = 2*s + (v >> 2);
  q = v & 3;
}

// ---------------- fused: router (b<2048) | W1 transpose | W2 transpose ----------------
__global__ __launch_bounds__(256) void k_fused(
    const float* __restrict__ x, const float* __restrict__ Wr,
    const float* __restrict__ br, float* __restrict__ out_logits,
    float* __restrict__ out_idx, int4* __restrict__ info,
    int* __restrict__ counts, unsigned short* __restrict__ Xbf,
    const float* __restrict__ W1, unsigned short* __restrict__ W1b,
    const float* __restrict__ W2, unsigned short* __restrict__ W2b)
{
  __shared__ float tileS[128][33];
  __shared__ int bc[8];
  int b = blockIdx.x;
  int tid = threadIdx.x;

  if (b < RBC) {
    // ---- router: 4 tokens per block, one wave each; non-atomic counts ----
    if (tid < 8) bc[tid] = 0;
    __syncthreads();
    int t = b * 4 + (tid >> 6);
    int lane = tid & 63;
    const float4* xr = (const float4*)(x + (size_t)t * C_);
    float4 x0 = xr[lane*2], x1 = xr[lane*2+1];
    uint4 pk;
    pk.x = f2bf(x0.x) | (f2bf(x0.y) << 16);
    pk.y = f2bf(x0.z) | (f2bf(x0.w) << 16);
    pk.z = f2bf(x1.x) | (f2bf(x1.y) << 16);
    pk.w = f2bf(x1.z) | (f2bf(x1.w) << 16);
    *(uint4*)(Xbf + (size_t)t * C_ + lane*8) = pk;

    float xs[8] = {x0.x,x0.y,x0.z,x0.w,x1.x,x1.y,x1.z,x1.w};
    float acc[8] = {0,0,0,0,0,0,0,0};
    #pragma unroll
    for (int j = 0; j < 8; j++) {
      const float4* w = (const float4*)(Wr + (size_t)(lane*8+j) * E_);
      float4 w0 = w[0], w1 = w[1];
      float we[8] = {w0.x,w0.y,w0.z,w0.w,w1.x,w1.y,w1.z,w1.w};
      #pragma unroll
      for (int e = 0; e < 8; e++) acc[e] += xs[j] * we[e];
    }
    #pragma unroll
    for (int off = 1; off < 64; off <<= 1) {
      #pragma unroll
      for (int e = 0; e < 8; e++) acc[e] += __shfl_xor(acc[e], off, 64);
    }
    #pragma unroll
    for (int e = 0; e < 8; e++) acc[e] += br[e];
    if (lane == 0) {
      #pragma unroll
      for (int e = 0; e < 8; e++) out_logits[t*8 + e] = acc[e];
      int i0 = 0; float v0 = acc[0];
      #pragma unroll
      for (int e = 1; e < 8; e++) if (acc[e] > v0) { v0 = acc[e]; i0 = e; }
      int i1 = -1; float v1 = -1e30f;
      #pragma unroll
      for (int e = 0; e < 8; e++) if (e != i0 && acc[e] > v1) { v1 = acc[e]; i1 = e; }
      float d = expf(v1 - v0);
      float s1 = d / (1.0f + d);
      float s0 = 1.0f - s1;
      out_idx[t*2]     = (float)i0;
      out_idx[t*2 + 1] = (float)i1;
      info[t] = make_int4(i0, i1, __float_as_int(s0), __float_as_int(s1));
      atomicAdd(&bc[i0], 1);     // LDS atomic, block-local
      atomicAdd(&bc[i1], 1);
    }
    __syncthreads();
    if (tid < 8) counts[b*8 + tid] = bc[tid];   // full write: no memset needed
    return;
  }

  // ---- weight transposes: fp32[R][S] -> bf16[S][R] ----
  const float* in; unsigned short* outp; int R, S, bx, by, bz;
  if (b < 2*RBC) {
    int bb = b - RBC;                    // W1: R=C(512), S=H(2048)
    in = W1; outp = W1b; R = C_; S = H_;
    bx = bb & 63; by = (bb >> 6) & 3; bz = bb >> 8;
  } else {
    int bb = b - 2*RBC;                  // W2: R=H(2048), S=C(512)
    in = W2; outp = W2b; R = H_; S = C_;
    bx = bb & 15; by = (bb >> 4) & 15; bz = bb >> 8;
  }
  size_t zo = (size_t)bz * R * S;
  in += zo; outp += zo;
  int r0 = by * 128, s0 = bx * 32;
  #pragma unroll
  for (int i = 0; i < 16; i++) {
    int lin = i*256 + tid;
    int rr = lin >> 5, ss = lin & 31;
    tileS[rr][ss] = in[(size_t)(r0 + rr) * S + s0 + ss];
  }
  __syncthreads();
  #pragma unroll
  for (int i = 0; i < 4; i++) {
    int lin = i*256 + tid;
    int ss = lin >> 5, rq = lin & 31;
    ushort4 v;
    v.x = (unsigned short)f2bf(tileS[rq*4+0][ss]);
    v.y = (unsigned short)f2bf(tileS[rq*4+1][ss]);
    v.z = (unsigned short)f2bf(tileS[rq*4+2][ss]);
    v.w = (unsigned short)f2bf(tileS[rq*4+3][ss]);
    *(ushort4*)(outp + (size_t)(s0 + ss) * R + r0 + rq*4) = v;
  }
}

// ---------------- prefix+scatter fused: 128 blocks x 64 threads ----------------
__global__ __launch_bounds__(64) void k_prefscatter(
    const int* __restrict__ counts, const int4* __restrict__ info,
    int* __restrict__ tokl, int2* __restrict__ slots2,
    int* __restrict__ offs, int* __restrict__ t1s, int* __restrict__ qc)
{
  __shared__ int full_s[8][8];
  __shared__ int part_s[8][8];
  __shared__ int tot_s[8];
  __shared__ int off_s[9];
  __shared__ int cur[8];
  int c = blockIdx.x, t = threadIdx.x;
  int e = t & 7, g = t >> 3;          // 8 experts x 8 groups of 256 router-blocks
  int lim = c * 16;                   // chunk c covers router blocks [0, c*16)
  int full = 0, part = 0;
  for (int i = 0; i < 256; i++) {
    int rb = g*256 + i;
    int v = counts[rb*8 + e];
    full += v;
    if (rb < lim) part += v;
  }
  full_s[e][g] = full; part_s[e][g] = part;
  __syncthreads();
  if (t < 8) {
    int s = 0;
    #pragma unroll
    for (int gg = 0; gg < 8; gg++) s += full_s[t][gg];
    tot_s[t] = s;
  }
  __syncthreads();
  if (t == 0) {
    int o = 0;
    off_s[0] = 0;
    for (int ee = 0; ee < 8; ee++) { o += tot_s[ee]; off_s[ee+1] = o; }
    if (c == 0) {
      offs[0] = 0; t1s[0] = 0;
      qc[0] = 0; qc[1] = 0;           // reset GEMM tile queues
      int tt = 0;
      for (int ee = 0; ee < 8; ee++) {
        offs[ee+1] = off_s[ee+1];
        tt += (tot_s[ee] + 127) >> 7;
        t1s[ee+1] = tt;
      }
    }
  }
  __syncthreads();
  if (t < 8) {
    int mg = c >> 4;                  // lim/256
    int bse = off_s[t];
    #pragma unroll
    for (int gg = 0; gg < 8; gg++) if (gg < mg) bse += full_s[t][gg];
    bse += part_s[t][mg];
    cur[t] = bse;
  }
  __syncthreads();
  int tok = c*64 + t;
  int4 nfo = info[tok];
  int r0 = atomicAdd(&cur[nfo.x], 1);
  int r1 = atomicAdd(&cur[nfo.y], 1);
  tokl[r0] = tok;
  tokl[r1] = tok;
  slots2[tok] = make_int2(r0, r1);
}

// Inner K-loop (R5 structure, best measured): 8 waves, wave tile 64x32,
// tri-buffered LDS, ONE barrier per K-step, counted vmcnt(2),
// stage-after-barrier, 2 setprio MFMA clusters.
// Hazards: step k reads buf[k%3], stages buf[(k+2)%3] post-barrier; all
// waves drained their step-(k-1) reads of that buffer (lgkmcnt(0)) before
// the barrier, and each wave's vmcnt(2) retires its stage(k) writes.
#define KLOOP(KI)                                                              \
  {                                                                            \
    int cOff = 0, sOff = 2*8192;                                               \
    for (int ki = 0; ki < (KI); ki++) {                                        \
      if (ki + 1 < (KI))                                                       \
        asm volatile("s_waitcnt vmcnt(2)" ::: "memory");                       \
      else                                                                     \
        asm volatile("s_waitcnt vmcnt(0)" ::: "memory");                       \
      asm volatile("s_barrier" ::: "memory");                                  \
      if (ki + 2 < (KI)) {                                                     \
        int off_ = (ki + 2) * 32;                                              \
        unsigned short* nb_ = AB + sOff;                                       \
        g2l16(ga + off_, nb_ + lao);                                           \
        g2l16(gb + off_, nb_ + lbo);                                           \
      }                                                                        \
      const unsigned short* Ap_ = AB + cOff;                                   \
      const unsigned short* Bp_ = Ap_ + 4096;                                  \
      bf16x8 af0 = *(const bf16x8*)&Ap_[wm*32 + 0*512 + rbase];                \
      bf16x8 af1 = *(const bf16x8*)&Ap_[wm*32 + 1*512 + rbase];                \
      bf16x8 bf0 = *(const bf16x8*)&Bp_[wn*32 + 0*512 + rbase];                \
      bf16x8 bf1 = *(const bf16x8*)&Bp_[wn*32 + 1*512 + rbase];                \
      __builtin_amdgcn_s_setprio(1);                                           \
      acc[0][0] = __builtin_amdgcn_mfma_f32_16x16x32_bf16(af0, bf0, acc[0][0], 0, 0, 0); \
      acc[0][1] = __builtin_amdgcn_mfma_f32_16x16x32_bf16(af0, bf1, acc[0][1], 0, 0, 0); \
      acc[1][0] = __builtin_amdgcn_mfma_f32_16x16x32_bf16(af1, bf0, acc[1][0], 0, 0, 0); \
      acc[1][1] = __builtin_amdgcn_mfma_f32_16x16x32_bf16(af1, bf1, acc[1][1], 0, 0, 0); \
      __builtin_amdgcn_s_setprio(0);                                           \
      bf16x8 af2 = *(const bf16x8*)&Ap_[wm*32 + 2*512 + rbase];                \
      bf16x8 af3 = *(const bf16x8*)&Ap_[wm*32 + 3*512 + rbase];                \
      __builtin_amdgcn_s_setprio(1);                                           \
      acc[2][0] = __builtin_amdgcn_mfma_f32_16x16x32_bf16(af2, bf0, acc[2][0], 0, 0, 0); \
      acc[2][1] = __builtin_amdgcn_mfma_f32_16x16x32_bf16(af2, bf1, acc[2][1], 0, 0, 0); \
      acc[3][0] = __builtin_amdgcn_mfma_f32_16x16x32_bf16(af3, bf0, acc[3][0], 0, 0, 0); \
      acc[3][1] = __builtin_amdgcn_mfma_f32_16x16x32_bf16(af3, bf1, acc[3][1], 0, 0, 0); \
      __builtin_amdgcn_s_setprio(0);                                           \
      asm volatile("s_waitcnt lgkmcnt(0)" ::: "memory");                       \
      cOff += 8192; if (cOff == 3*8192) cOff = 0;                              \
      sOff += 8192; if (sOff == 3*8192) sOff = 0;                              \
    }                                                                          \
  }

// ---------------- grouped GEMM layer 1: Hs = relu(Xrows @ W1 + b1) ----------------
// PERSISTENT blocks + dynamic tile queue (removes shift/tail quantization).
// 128x128 tile, BK=32, 8 waves, wave tile 64x32, R5 KLOOP.
__global__ __launch_bounds__(512) void k_gemm1(
    const unsigned short* __restrict__ Xbf, const int* __restrict__ tokl,
    const unsigned short* __restrict__ W1b,
    const float* __restrict__ b1, unsigned short* __restrict__ Hs,
    const int* __restrict__ offs, const int* __restrict__ t1s,
    int* __restrict__ qc)
{
  __shared__ __align__(16) unsigned short AB[3*8192];   // 48 KB
  __shared__ int tsh;
  int tid = threadIdx.x, lane = tid & 63, w = tid >> 6;
  int wm = (w >> 2) * 64, wn = (w & 3) * 32;
  int quad = lane >> 4, l16 = lane & 15;
  int rbase = (l16>>1)*64 + ((((l16&1)<<2) + quad) ^ (l16>>1))*8;
  const int KI = C_ / 32;   // 16
  int nTiles = t1s[8] * 16;
  const f32x4 zero = {0.f, 0.f, 0.f, 0.f};

  for (;;) {
    if (tid == 0) tsh = atomicAdd(qc, 1);
    __syncthreads();                 // broadcast tile; also fences prior epilogue
    int ti = tsh;
    if (ti >= nTiles) break;         // uniform exit
    int n0 = (ti & 15) * 128;
    int mt = ti >> 4;
    int e = 0;
    #pragma unroll
    for (int i = 0; i < 7; i++) if (mt >= t1s[i+1]) e++;
    int row0 = offs[e] + (mt - t1s[e]) * 128;
    int rowEnd = offs[e+1];
    f32x4 acc[4][2];
    #pragma unroll
    for (int i = 0; i < 4; i++)
      #pragma unroll
      for (int j = 0; j < 2; j++) acc[i][j] = zero;
    const unsigned short* Bsrc = W1b + ((size_t)e * H_ + n0) * C_;

    const unsigned short* ga; const unsigned short* gb;
    int lao, lbo;
    {
      int L = w*64 + lane;
      int brow, q; stage_decode(L, brow, q);
      int gr = row0 + brow; gr = gr < NASN-1 ? gr : NASN-1;
      int trow = tokl[gr];
      ga = Xbf + (size_t)trow * C_ + q*8;
      gb = Bsrc + (size_t)brow * C_ + q*8;
      lao = w*512;
      lbo = 4096 + w*512;
    }

    // prologue: tiles 0,1 -> buffers 0,1
    g2l16(ga, AB + lao);             g2l16(gb, AB + lbo);
    g2l16(ga + 32, AB + 8192 + lao); g2l16(gb + 32, AB + 8192 + lbo);

    KLOOP(KI);
    __syncthreads();                 // KLOOP done before Lt overwrites buffers

    // epilogue: per-wave LDS transpose (64x32, 4KB/wave) -> coalesced stores
    unsigned short* Lt = AB + w*2048;
    #pragma unroll
    for (int j = 0; j < 2; j++) {
      int n = n0 + wn + j*16 + l16;
      float bias = b1[e * H_ + n];
      #pragma unroll
      for (int i = 0; i < 4; i++)
        #pragma unroll
        for (int r = 0; r < 4; r++) {
          float v = acc[i][j][r] + bias;
          Lt[(i*16 + quad*4 + r)*32 + j*16 + l16] = (unsigned short)f2bf(v > 0.f ? v : 0.f);
        }
    }
    #pragma unroll
    for (int it = 0; it < 4; it++) {
      int rloc = it*16 + (lane >> 2);
      int m = row0 + wm + rloc;
      uint4 vv = *(uint4*)&Lt[rloc*32 + (lane & 3)*8];
      if (m < rowEnd)
        *(uint4*)(Hs + (size_t)m * H_ + n0 + wn + (lane & 3)*8) = vv;
    }
  }
}

// ---------------- grouped GEMM layer 2: Ys(bf16) = Hs @ W2 + b2 ----------------
// Persistent + dynamic queue; same 8-wave R5 structure; KI=64.
__global__ __launch_bounds__(512) void k_gemm2(
    const unsigned short* __restrict__ Hs, const unsigned short* __restrict__ W2b,
    const float* __restrict__ b2, unsigned short* __restrict__ Ys,
    const int* __restrict__ offs, const int* __restrict__ t1s,
    int* __restrict__ qc)
{
  __shared__ __align__(16) unsigned short AB[3*8192];   // 48 KB
  __shared__ int tsh;
  int tid = threadIdx.x, lane = tid & 63, w = tid >> 6;
  int wm = (w >> 2) * 64, wn = (w & 3) * 32;
  int quad = lane >> 4, l16 = lane & 15;
  int rbase = (l16>>1)*64 + ((((l16&1)<<2) + quad) ^ (l16>>1))*8;
  const int KI = H_ / 32;   // 64
  int nTiles = t1s[8] * 4;
  const f32x4 zero = {0.f, 0.f, 0.f, 0.f};

  for (;;) {
    if (tid == 0) tsh = atomicAdd(qc, 1);
    __syncthreads();
    int ti = tsh;
    if (ti >= nTiles) break;
    int n0 = (ti & 3) * 128;
    int mt = ti >> 2;
    int e = 0;
    #pragma unroll
    for (int i = 0; i < 7; i++) if (mt >= t1s[i+1]) e++;
    int row0 = offs[e] + (mt - t1s[e]) * 128;
    int rowEnd = offs[e+1];
    f32x4 acc[4][2];
    #pragma unroll
    for (int i = 0; i < 4; i++)
      #pragma unroll
      for (int j = 0; j < 2; j++) acc[i][j] = zero;
    const unsigned short* Bsrc = W2b + ((size_t)e * C_ + n0) * H_;

    const unsigned short* ga; const unsigned short* gb;
    int lao, lbo;
    {
      int L = w*64 + lane;
      int brow, q; stage_decode(L, brow, q);
      int gr = row0 + brow; gr = gr < NASN-1 ? gr : NASN-1;
      ga = Hs + (size_t)gr * H_ + q*8;
      gb = Bsrc + (size_t)brow * H_ + q*8;
      lao = w*512;
      lbo = 4096 + w*512;
    }

    g2l16(ga, AB + lao);             g2l16(gb, AB + lbo);
    g2l16(ga + 32, AB + 8192 + lao); g2l16(gb + 32, AB + 8192 + lbo);

    KLOOP(KI);
    __syncthreads();

    // epilogue: per-wave LDS transpose (64x32, 4KB/wave) -> coalesced stores
    unsigned short* Lt = AB + w*2048;
    #pragma unroll
    for (int j = 0; j < 2; j++) {
      int n = n0 + wn + j*16 + l16;
      float bias = b2[e * C_ + n];
      #pragma unroll
      for (int i = 0; i < 4; i++)
        #pragma unroll
        for (int r = 0; r < 4; r++)
          Lt[(i*16 + quad*4 + r)*32 + j*16 + l16] =
              (unsigned short)f2bf(acc[i][j][r] + bias);
    }
    #pragma unroll
    for (int it = 0; it < 4; it++) {
      int rloc = it*16 + (lane >> 2);
      int m = row0 + wm + rloc;
      uint4 vv = *(uint4*)&Lt[rloc*32 + (lane & 3)*8];
      if (m < rowEnd)
        *(uint4*)(Ys + (size_t)m * C_ + n0 + wn + (lane & 3)*8) = vv;
    }
  }
}

// ---------------- combine: out[t] = g0*Ys[s0] + g1*Ys[s1] (bf16 Ys) ----------------
__global__ __launch_bounds__(256) void k_combine(
    const unsigned short* __restrict__ Ys, const int4* __restrict__ info,
    const int2* __restrict__ slots2, float* __restrict__ outp)
{
  int t = blockIdx.x * 4 + (threadIdx.x >> 6);
  int lane = threadIdx.x & 63;
  int4 nfo = info[t];
  int2 ss = slots2[t];
  float g0 = __int_as_float(nfo.z), g1 = __int_as_float(nfo.w);
  uint4 a = *(const uint4*)(Ys + (size_t)ss.x * C_ + lane*8);
  uint4 bb = *(const uint4*)(Ys + (size_t)ss.y * C_ + lane*8);
  unsigned int au[4] = {a.x, a.y, a.z, a.w};
  unsigned int bu[4] = {bb.x, bb.y, bb.z, bb.w};
  float vals[8];
  #pragma unroll
  for (int q = 0; q < 4; q++) {
    vals[q*2]   = g0*bf2f(au[q])       + g1*bf2f(bu[q]);
    vals[q*2+1] = g0*bf2f(au[q] >> 16) + g1*bf2f(bu[q] >> 16);
  }
  float4 o0, o1;
  o0.x = vals[0]; o0.y = vals[1]; o0.z = vals[2]; o0.w = vals[3];
  o1.x = vals[4]; o1.y = vals[5]; o1.z = vals[6]; o1.w = vals[7];
  float4* o = (float4*)(outp + (size_t)t * C_ + lane*8);
  o[0] = o0;
  o[1] = o1;
}

extern "C" void kernel_launch(void* const* d_in, const int* in_sizes, int n_in,
                              void* d_out, int out_size, void* d_ws, size_t ws_size,
                              hipStream_t stream)
{
  const float* x  = (const float*)d_in[0];
  const float* Wr = (const float*)d_in[1];
  const float* br = (const float*)d_in[2];
  const float* W1 = (const float*)d_in[3];
  const float* b1 = (const float*)d_in[4];
  const float* W2 = (const float*)d_in[5];
  const float* b2 = (const float*)d_in[6];
  float* out = (float*)d_out;   // [logits 65536 | idx 16384 | out 4194304]
  char* ws = (char*)d_ws;

  int*  counts = (int*)(ws + WS_COUNTS);
  int*  offs   = (int*)(ws + WS_OFFS);
  int*  t1s    = (int*)(ws + WS_T1S);
  int*  qc     = (int*)(ws + WS_QC);
  int4* info   = (int4*)(ws + WS_INFO);
  int*  tokl   = (int*)(ws + WS_TOKL);
  int2* slots2 = (int2*)(ws + WS_SLOTS);
  unsigned short* Xbf = (unsigned short*)(ws + WS_XBF);
  unsigned short* W1b = (unsigned short*)(ws + WS_W1B);
  unsigned short* W2b = (unsigned short*)(ws + WS_W2B);
  unsigned short* Hs  = (unsigned short*)(ws + WS_HS);
  unsigned short* Ys  = (unsigned short*)(ws + WS_YS);  // aliases Xbf+W1b

  // 5 launches: router+transposes fused, prefix+scatter fused (also resets
  // the GEMM tile queues), persistent-GEMM1, persistent-GEMM2, combine.
  k_fused<<<3*RBC, 256, 0, stream>>>(x, Wr, br, out, out + 65536, info,
                                     counts, Xbf, W1, W1b, W2, W2b);
  k_prefscatter<<<128, 64, 0, stream>>>(counts, info, tokl, slots2, offs, t1s, qc);
  k_gemm1<<<768, 512, 0, stream>>>(Xbf, tokl, W1b, b1, Hs, offs, t1s, qc);
  k_gemm2<<<512, 512, 0, stream>>>(Hs, W2b, b2, Ys, offs, t1s, qc + 1);
  k_combine<<<NTOK/4, 256, 0, stream>>>(Ys, info, slots2, out + 81920);
}

// Round 9
// 260.608 us; speedup vs baseline: 1.1480x; 1.1480x over previous
//
#include <hip/hip_runtime.h>
#include <hip/hip_bf16.h>

// Problem dims
#define NTOK 8192       // B*T
#define NASN 16384      // NTOK * K(=2)
#define C_ 512
#define H_ 2048
#define E_ 8
#define RBC 2048        // router blocks (4 tokens each) = count granularity

typedef __bf16 bf16x8 __attribute__((ext_vector_type(8)));
typedef float f32x4 __attribute__((ext_vector_type(4)));

// Workspace layout (bytes). Total ~109.5 MB.
#define WS_COUNTS 0                              // RBC*8*4 = 64 KB (written, not atomically)
#define WS_OFFS   65536                          // 9*4 -> pad 256
#define WS_T1S    65792                          // 9*4
#define WS_INFO   66048                          // NTOK*16
#define WS_TOKL   (WS_INFO + NTOK*16)            // NASN*4
#define WS_SLOTS  (WS_TOKL + NASN*4)             // NTOK*8 (int2)
#define WS_XBF    (WS_SLOTS + NTOK*8)            // NTOK*C_*2 bf16 token-ordered x
#define WS_W1B    (WS_XBF + (size_t)NTOK*C_*2)   // E*H*C bf16, [e][h][c]
#define WS_W2B    (WS_W1B + (size_t)E_*H_*C_*2)  // E*C*H bf16, [e][c][h]
#define WS_HS     (WS_W2B + (size_t)E_*H_*C_*2)  // NASN*H bf16 hidden acts
// Ys (bf16, NASN*C_*2 = 16.78 MB) aliases Xbf+W1b (25.2 MB, dead by k_gemm2).
#define WS_YS     WS_XBF

__device__ __forceinline__ unsigned int f2bf(float f) {
  __hip_bfloat16 h = __float2bfloat16(f);
  return (unsigned int)*(unsigned short*)&h;
}
__device__ __forceinline__ float bf2f(unsigned int u) {
  return __int_as_float((u & 0xffffu) << 16);
}

// async global->LDS, 16B per lane; LDS dest = wave-uniform base + lane*16
__device__ __forceinline__ void g2l16(const unsigned short* g, unsigned short* l) {
  __builtin_amdgcn_global_load_lds(
      (const __attribute__((address_space(1))) unsigned int*)g,
      (__attribute__((address_space(3))) unsigned int*)l, 16, 0, 0);
}

// Pair-interleaved XOR LDS layout for a [rows x 32 ushort] panel:
// 16B chunk of (row r, k-chunk q) at linear chunk (r>>1)*8 + slot,
// slot = ((r&1)*4 + q) ^ ((r>>1)&7).  Full 32-bank coverage on fragment reads.
__device__ __forceinline__ void stage_decode(int L, int& brow, int& q) {
  int s = L >> 3, slot = L & 7;
  int v = slot ^ (s & 7);
  brow = 2*s + (v >> 2);
  q = v & 3;
}

// ---------------- fused: router (b<2048) | W1 transpose | W2 transpose ----------------
__global__ __launch_bounds__(256) void k_fused(
    const float* __restrict__ x, const float* __restrict__ Wr,
    const float* __restrict__ br, float* __restrict__ out_logits,
    float* __restrict__ out_idx, int4* __restrict__ info,
    int* __restrict__ counts, unsigned short* __restrict__ Xbf,
    const float* __restrict__ W1, unsigned short* __restrict__ W1b,
    const float* __restrict__ W2, unsigned short* __restrict__ W2b)
{
  __shared__ float tileS[128][33];
  __shared__ int bc[8];
  int b = blockIdx.x;
  int tid = threadIdx.x;

  if (b < RBC) {
    // ---- router: 4 tokens per block, one wave each; non-atomic counts ----
    if (tid < 8) bc[tid] = 0;
    __syncthreads();
    int t = b * 4 + (tid >> 6);
    int lane = tid & 63;
    const float4* xr = (const float4*)(x + (size_t)t * C_);
    float4 x0 = xr[lane*2], x1 = xr[lane*2+1];
    uint4 pk;
    pk.x = f2bf(x0.x) | (f2bf(x0.y) << 16);
    pk.y = f2bf(x0.z) | (f2bf(x0.w) << 16);
    pk.z = f2bf(x1.x) | (f2bf(x1.y) << 16);
    pk.w = f2bf(x1.z) | (f2bf(x1.w) << 16);
    *(uint4*)(Xbf + (size_t)t * C_ + lane*8) = pk;

    float xs[8] = {x0.x,x0.y,x0.z,x0.w,x1.x,x1.y,x1.z,x1.w};
    float acc[8] = {0,0,0,0,0,0,0,0};
    #pragma unroll
    for (int j = 0; j < 8; j++) {
      const float4* w = (const float4*)(Wr + (size_t)(lane*8+j) * E_);
      float4 w0 = w[0], w1 = w[1];
      float we[8] = {w0.x,w0.y,w0.z,w0.w,w1.x,w1.y,w1.z,w1.w};
      #pragma unroll
      for (int e = 0; e < 8; e++) acc[e] += xs[j] * we[e];
    }
    #pragma unroll
    for (int off = 1; off < 64; off <<= 1) {
      #pragma unroll
      for (int e = 0; e < 8; e++) acc[e] += __shfl_xor(acc[e], off, 64);
    }
    #pragma unroll
    for (int e = 0; e < 8; e++) acc[e] += br[e];
    if (lane == 0) {
      #pragma unroll
      for (int e = 0; e < 8; e++) out_logits[t*8 + e] = acc[e];
      int i0 = 0; float v0 = acc[0];
      #pragma unroll
      for (int e = 1; e < 8; e++) if (acc[e] > v0) { v0 = acc[e]; i0 = e; }
      int i1 = -1; float v1 = -1e30f;
      #pragma unroll
      for (int e = 0; e < 8; e++) if (e != i0 && acc[e] > v1) { v1 = acc[e]; i1 = e; }
      float d = expf(v1 - v0);
      float s1 = d / (1.0f + d);
      float s0 = 1.0f - s1;
      out_idx[t*2]     = (float)i0;
      out_idx[t*2 + 1] = (float)i1;
      info[t] = make_int4(i0, i1, __float_as_int(s0), __float_as_int(s1));
      atomicAdd(&bc[i0], 1);     // LDS atomic, block-local
      atomicAdd(&bc[i1], 1);
    }
    __syncthreads();
    if (tid < 8) counts[b*8 + tid] = bc[tid];   // full write: no memset needed
    return;
  }

  // ---- weight transposes: fp32[R][S] -> bf16[S][R] ----
  const float* in; unsigned short* outp; int R, S, bx, by, bz;
  if (b < 2*RBC) {
    int bb = b - RBC;                    // W1: R=C(512), S=H(2048)
    in = W1; outp = W1b; R = C_; S = H_;
    bx = bb & 63; by = (bb >> 6) & 3; bz = bb >> 8;
  } else {
    int bb = b - 2*RBC;                  // W2: R=H(2048), S=C(512)
    in = W2; outp = W2b; R = H_; S = C_;
    bx = bb & 15; by = (bb >> 4) & 15; bz = bb >> 8;
  }
  size_t zo = (size_t)bz * R * S;
  in += zo; outp += zo;
  int r0 = by * 128, s0 = bx * 32;
  // float4 loads: 16B/lane, 4 iters (was 16 iters of scalar 4B loads)
  #pragma unroll
  for (int i = 0; i < 4; i++) {
    int lin = i*256 + tid;               // 1024 = 128 rows x 8 quads
    int rr = lin >> 3, sq = lin & 7;
    float4 v = *(const float4*)(in + (size_t)(r0 + rr) * S + s0 + sq*4);
    tileS[rr][sq*4+0] = v.x;
    tileS[rr][sq*4+1] = v.y;
    tileS[rr][sq*4+2] = v.z;
    tileS[rr][sq*4+3] = v.w;
  }
  __syncthreads();
  #pragma unroll
  for (int i = 0; i < 4; i++) {
    int lin = i*256 + tid;
    int ss = lin >> 5, rq = lin & 31;
    ushort4 v;
    v.x = (unsigned short)f2bf(tileS[rq*4+0][ss]);
    v.y = (unsigned short)f2bf(tileS[rq*4+1][ss]);
    v.z = (unsigned short)f2bf(tileS[rq*4+2][ss]);
    v.w = (unsigned short)f2bf(tileS[rq*4+3][ss]);
    *(ushort4*)(outp + (size_t)(s0 + ss) * R + r0 + rq*4) = v;
  }
}

// ---------------- prefix+scatter fused: 128 blocks x 256 threads ----------------
// 256 threads: thread (e, g) with g in [0,32) scans 64 router-blocks (was 64
// threads x 256-iter scans at 0.5 waves/CU -- latency-bound).  Block c
// self-computes per-expert slot bases for its 64 tokens; block 0 writes
// offs/t1s for the GEMMs.
__global__ __launch_bounds__(256) void k_prefscatter(
    const int* __restrict__ counts, const int4* __restrict__ info,
    int* __restrict__ tokl, int2* __restrict__ slots2,
    int* __restrict__ offs, int* __restrict__ t1s)
{
  __shared__ int full_s[8][32];
  __shared__ int part_s[8][32];
  __shared__ int tot_s[8];
  __shared__ int off_s[9];
  __shared__ int cur[8];
  int c = blockIdx.x, t = threadIdx.x;
  int e = t & 7, g = t >> 3;          // 8 experts x 32 groups of 64 router-blocks
  int lim = c * 16;                   // chunk c covers router blocks [0, c*16)
  int full = 0, part = 0;
  for (int i = 0; i < 64; i++) {
    int rb = g*64 + i;
    int v = counts[rb*8 + e];
    full += v;
    if (rb < lim) part += v;
  }
  full_s[e][g] = full; part_s[e][g] = part;
  __syncthreads();
  if (t < 8) {
    int s = 0;
    #pragma unroll
    for (int gg = 0; gg < 32; gg++) s += full_s[t][gg];
    tot_s[t] = s;
  }
  __syncthreads();
  if (t == 0) {
    int o = 0;
    off_s[0] = 0;
    for (int ee = 0; ee < 8; ee++) { o += tot_s[ee]; off_s[ee+1] = o; }
    if (c == 0) {
      offs[0] = 0; t1s[0] = 0;
      int tt = 0;
      for (int ee = 0; ee < 8; ee++) {
        offs[ee+1] = off_s[ee+1];
        tt += (tot_s[ee] + 127) >> 7;
        t1s[ee+1] = tt;
      }
    }
  }
  __syncthreads();
  if (t < 8) {
    int mg = c >> 2;                  // lim/64
    int bse = off_s[t];
    #pragma unroll
    for (int gg = 0; gg < 32; gg++) if (gg < mg) bse += full_s[t][gg];
    bse += part_s[t][mg];
    cur[t] = bse;
  }
  __syncthreads();
  if (t < 64) {
    int tok = c*64 + t;
    int4 nfo = info[tok];
    int r0 = atomicAdd(&cur[nfo.x], 1);
    int r1 = atomicAdd(&cur[nfo.y], 1);
    tokl[r0] = tok;
    tokl[r1] = tok;
    slots2[tok] = make_int2(r0, r1);
  }
}

// Inner K-loop (R5 structure, best measured 61.4us gemm2): 8 waves, wave
// tile 64x32, tri-buffered LDS, ONE barrier per K-step, counted vmcnt(2),
// stage-after-barrier, 2 setprio MFMA clusters.
// Hazards: step k reads buf[k%3] (staged step k-2, retired by step-(k)'s
// vmcnt(2) since g2l16s retire in order), stages buf[(k+2)%3] post-barrier
// (all waves' step-(k-1) reads of it drained via lgkmcnt(0) pre-barrier).
#define KLOOP(KI)                                                              \
  {                                                                            \
    int cOff = 0, sOff = 2*8192;                                               \
    for (int ki = 0; ki < (KI); ki++) {                                        \
      if (ki + 1 < (KI))                                                       \
        asm volatile("s_waitcnt vmcnt(2)" ::: "memory");                       \
      else                                                                     \
        asm volatile("s_waitcnt vmcnt(0)" ::: "memory");                       \
      asm volatile("s_barrier" ::: "memory");                                  \
      if (ki + 2 < (KI)) {                                                     \
        int off_ = (ki + 2) * 32;                                              \
        unsigned short* nb_ = AB + sOff;                                       \
        g2l16(ga + off_, nb_ + lao);                                           \
        g2l16(gb + off_, nb_ + lbo);                                           \
      }                                                                        \
      const unsigned short* Ap_ = AB + cOff;                                   \
      const unsigned short* Bp_ = Ap_ + 4096;                                  \
      bf16x8 af0 = *(const bf16x8*)&Ap_[wm*32 + 0*512 + rbase];                \
      bf16x8 af1 = *(const bf16x8*)&Ap_[wm*32 + 1*512 + rbase];                \
      bf16x8 bf0 = *(const bf16x8*)&Bp_[wn*32 + 0*512 + rbase];                \
      bf16x8 bf1 = *(const bf16x8*)&Bp_[wn*32 + 1*512 + rbase];                \
      __builtin_amdgcn_s_setprio(1);                                           \
      acc[0][0] = __builtin_amdgcn_mfma_f32_16x16x32_bf16(af0, bf0, acc[0][0], 0, 0, 0); \
      acc[0][1] = __builtin_amdgcn_mfma_f32_16x16x32_bf16(af0, bf1, acc[0][1], 0, 0, 0); \
      acc[1][0] = __builtin_amdgcn_mfma_f32_16x16x32_bf16(af1, bf0, acc[1][0], 0, 0, 0); \
      acc[1][1] = __builtin_amdgcn_mfma_f32_16x16x32_bf16(af1, bf1, acc[1][1], 0, 0, 0); \
      __builtin_amdgcn_s_setprio(0);                                           \
      bf16x8 af2 = *(const bf16x8*)&Ap_[wm*32 + 2*512 + rbase];                \
      bf16x8 af3 = *(const bf16x8*)&Ap_[wm*32 + 3*512 + rbase];                \
      __builtin_amdgcn_s_setprio(1);                                           \
      acc[2][0] = __builtin_amdgcn_mfma_f32_16x16x32_bf16(af2, bf0, acc[2][0], 0, 0, 0); \
      acc[2][1] = __builtin_amdgcn_mfma_f32_16x16x32_bf16(af2, bf1, acc[2][1], 0, 0, 0); \
      acc[3][0] = __builtin_amdgcn_mfma_f32_16x16x32_bf16(af3, bf0, acc[3][0], 0, 0, 0); \
      acc[3][1] = __builtin_amdgcn_mfma_f32_16x16x32_bf16(af3, bf1, acc[3][1], 0, 0, 0); \
      __builtin_amdgcn_s_setprio(0);                                           \
      asm volatile("s_waitcnt lgkmcnt(0)" ::: "memory");                       \
      cOff += 8192; if (cOff == 3*8192) cOff = 0;                              \
      sOff += 8192; if (sOff == 3*8192) sOff = 0;                              \
    }                                                                          \
  }

// ---------------- grouped GEMM layer 1: Hs = relu(Xrows @ W1 + b1) ----------------
// 128x128 tile, BK=32, 8 waves (512 thr): wave grid 2M x 4N, each wave 64x32
// out (acc 4x2, 8 MFMA/K-step), stages 1 A-chunk + 1 B-chunk per K-step.
// 48KB LDS 3-buf, 1 barrier/K-step, vmcnt(2), pair-interleaved XOR LDS.
// STATIC grid (XCD-affine: same-A blocks are congruent mod 8 -> same L2).
__global__ __launch_bounds__(512) void k_gemm1(
    const unsigned short* __restrict__ Xbf, const int* __restrict__ tokl,
    const unsigned short* __restrict__ W1b,
    const float* __restrict__ b1, unsigned short* __restrict__ Hs,
    const int* __restrict__ offs, const int* __restrict__ t1s)
{
  __shared__ __align__(16) unsigned short AB[3*8192];   // 48 KB
  int b = blockIdx.x;
  int mo = b >> 7, rr = b & 127;
  int n0 = (rr >> 3) * 128;
  int mt = mo*8 + (rr & 7);
  if (mt >= t1s[8]) return;
  int e = 0;
  #pragma unroll
  for (int i = 0; i < 7; i++) if (mt >= t1s[e+1]) e++;
  int row0 = offs[e] + (mt - t1s[e]) * 128;
  int rowEnd = offs[e+1];
  int tid = threadIdx.x, lane = tid & 63, w = tid >> 6;
  int wm = (w >> 2) * 64, wn = (w & 3) * 32;
  int quad = lane >> 4, l16 = lane & 15;
  const f32x4 zero = {0.f, 0.f, 0.f, 0.f};
  f32x4 acc[4][2];
  #pragma unroll
  for (int i = 0; i < 4; i++)
    #pragma unroll
    for (int j = 0; j < 2; j++) acc[i][j] = zero;
  const unsigned short* Bsrc = W1b + ((size_t)e * H_ + n0) * C_;

  // staging: wave w loads A chunk L=w*64+lane and B chunk L=w*64+lane
  const unsigned short* ga; const unsigned short* gb;
  int lao, lbo;
  {
    int L = w*64 + lane;
    int brow, q; stage_decode(L, brow, q);
    int gr = row0 + brow; gr = gr < NASN-1 ? gr : NASN-1;
    int trow = tokl[gr];
    ga = Xbf + (size_t)trow * C_ + q*8;
    gb = Bsrc + (size_t)brow * C_ + q*8;
    lao = w*512;
    lbo = 4096 + w*512;
  }
  int rbase = (l16>>1)*64 + ((((l16&1)<<2) + quad) ^ (l16>>1))*8;
  const int KI = C_ / 32;   // 16

  // prologue: tiles 0,1 -> buffers 0,1
  g2l16(ga, AB + lao);            g2l16(gb, AB + lbo);
  g2l16(ga + 32, AB + 8192 + lao); g2l16(gb + 32, AB + 8192 + lbo);

  KLOOP(KI);
  __syncthreads();   // drain all waves' last-buffer reads before Lt overwrite

  // epilogue: per-wave LDS transpose (64x32, 4KB/wave) -> coalesced 16B stores
  unsigned short* Lt = AB + w*2048;
  #pragma unroll
  for (int j = 0; j < 2; j++) {
    int n = n0 + wn + j*16 + l16;
    float bias = b1[e * H_ + n];
    #pragma unroll
    for (int i = 0; i < 4; i++)
      #pragma unroll
      for (int r = 0; r < 4; r++) {
        float v = acc[i][j][r] + bias;
        Lt[(i*16 + quad*4 + r)*32 + j*16 + l16] = (unsigned short)f2bf(v > 0.f ? v : 0.f);
      }
  }
  #pragma unroll
  for (int it = 0; it < 4; it++) {
    int rloc = it*16 + (lane >> 2);
    int m = row0 + wm + rloc;
    uint4 vv = *(uint4*)&Lt[rloc*32 + (lane & 3)*8];
    if (m < rowEnd)
      *(uint4*)(Hs + (size_t)m * H_ + n0 + wn + (lane & 3)*8) = vv;
  }
}

// ---------------- grouped GEMM layer 2: Ys(bf16) = Hs @ W2 + b2 ----------------
// Same 8-wave structure; KI=64.  STATIC grid (XCD-affine).
__global__ __launch_bounds__(512) void k_gemm2(
    const unsigned short* __restrict__ Hs, const unsigned short* __restrict__ W2b,
    const float* __restrict__ b2, unsigned short* __restrict__ Ys,
    const int* __restrict__ offs, const int* __restrict__ t1s)
{
  __shared__ __align__(16) unsigned short AB[3*8192];   // 48 KB
  int b = blockIdx.x;
  int mo = b >> 5, rr = b & 31;
  int n0 = (rr >> 3) * 128;
  int mt = mo*8 + (rr & 7);
  if (mt >= t1s[8]) return;
  int e = 0;
  #pragma unroll
  for (int i = 0; i < 7; i++) if (mt >= t1s[e+1]) e++;
  int row0 = offs[e] + (mt - t1s[e]) * 128;
  int rowEnd = offs[e+1];
  int tid = threadIdx.x, lane = tid & 63, w = tid >> 6;
  int wm = (w >> 2) * 64, wn = (w & 3) * 32;
  int quad = lane >> 4, l16 = lane & 15;
  const f32x4 zero = {0.f, 0.f, 0.f, 0.f};
  f32x4 acc[4][2];
  #pragma unroll
  for (int i = 0; i < 4; i++)
    #pragma unroll
    for (int j = 0; j < 2; j++) acc[i][j] = zero;
  const unsigned short* Bsrc = W2b + ((size_t)e * C_ + n0) * H_;

  const unsigned short* ga; const unsigned short* gb;
  int lao, lbo;
  {
    int L = w*64 + lane;
    int brow, q; stage_decode(L, brow, q);
    int gr = row0 + brow; gr = gr < NASN-1 ? gr : NASN-1;
    ga = Hs + (size_t)gr * H_ + q*8;
    gb = Bsrc + (size_t)brow * H_ + q*8;
    lao = w*512;
    lbo = 4096 + w*512;
  }
  int rbase = (l16>>1)*64 + ((((l16&1)<<2) + quad) ^ (l16>>1))*8;
  const int KI = H_ / 32;   // 64

  g2l16(ga, AB + lao);            g2l16(gb, AB + lbo);
  g2l16(ga + 32, AB + 8192 + lao); g2l16(gb + 32, AB + 8192 + lbo);

  KLOOP(KI);
  __syncthreads();   // drain all waves' last-buffer reads before Lt overwrite

  // epilogue: per-wave LDS transpose (64x32, 4KB/wave) -> coalesced bf16 stores
  unsigned short* Lt = AB + w*2048;
  #pragma unroll
  for (int j = 0; j < 2; j++) {
    int n = n0 + wn + j*16 + l16;
    float bias = b2[e * C_ + n];
    #pragma unroll
    for (int i = 0; i < 4; i++)
      #pragma unroll
      for (int r = 0; r < 4; r++)
        Lt[(i*16 + quad*4 + r)*32 + j*16 + l16] =
            (unsigned short)f2bf(acc[i][j][r] + bias);
  }
  #pragma unroll
  for (int it = 0; it < 4; it++) {
    int rloc = it*16 + (lane >> 2);
    int m = row0 + wm + rloc;
    uint4 vv = *(uint4*)&Lt[rloc*32 + (lane & 3)*8];
    if (m < rowEnd)
      *(uint4*)(Ys + (size_t)m * C_ + n0 + wn + (lane & 3)*8) = vv;
  }
}

// ---------------- combine: out[t] = g0*Ys[s0] + g1*Ys[s1] (bf16 Ys) ----------------
__global__ __launch_bounds__(256) void k_combine(
    const unsigned short* __restrict__ Ys, const int4* __restrict__ info,
    const int2* __restrict__ slots2, float* __restrict__ outp)
{
  int t = blockIdx.x * 4 + (threadIdx.x >> 6);
  int lane = threadIdx.x & 63;
  int4 nfo = info[t];
  int2 ss = slots2[t];
  float g0 = __int_as_float(nfo.z), g1 = __int_as_float(nfo.w);
  uint4 a = *(const uint4*)(Ys + (size_t)ss.x * C_ + lane*8);
  uint4 bb = *(const uint4*)(Ys + (size_t)ss.y * C_ + lane*8);
  unsigned int au[4] = {a.x, a.y, a.z, a.w};
  unsigned int bu[4] = {bb.x, bb.y, bb.z, bb.w};
  float vals[8];
  #pragma unroll
  for (int q = 0; q < 4; q++) {
    vals[q*2]   = g0*bf2f(au[q])       + g1*bf2f(bu[q]);
    vals[q*2+1] = g0*bf2f(au[q] >> 16) + g1*bf2f(bu[q] >> 16);
  }
  float4 o0, o1;
  o0.x = vals[0]; o0.y = vals[1]; o0.z = vals[2]; o0.w = vals[3];
  o1.x = vals[4]; o1.y = vals[5]; o1.z = vals[6]; o1.w = vals[7];
  float4* o = (float4*)(outp + (size_t)t * C_ + lane*8);
  o[0] = o0;
  o[1] = o1;
}

extern "C" void kernel_launch(void* const* d_in, const int* in_sizes, int n_in,
                              void* d_out, int out_size, void* d_ws, size_t ws_size,
                              hipStream_t stream)
{
  const float* x  = (const float*)d_in[0];
  const float* Wr = (const float*)d_in[1];
  const float* br = (const float*)d_in[2];
  const float* W1 = (const float*)d_in[3];
  const float* b1 = (const float*)d_in[4];
  const float* W2 = (const float*)d_in[5];
  const float* b2 = (const float*)d_in[6];
  float* out = (float*)d_out;   // [logits 65536 | idx 16384 | out 4194304]
  char* ws = (char*)d_ws;

  int*  counts = (int*)(ws + WS_COUNTS);
  int*  offs   = (int*)(ws + WS_OFFS);
  int*  t1s    = (int*)(ws + WS_T1S);
  int4* info   = (int4*)(ws + WS_INFO);
  int*  tokl   = (int*)(ws + WS_TOKL);
  int2* slots2 = (int2*)(ws + WS_SLOTS);
  unsigned short* Xbf = (unsigned short*)(ws + WS_XBF);
  unsigned short* W1b = (unsigned short*)(ws + WS_W1B);
  unsigned short* W2b = (unsigned short*)(ws + WS_W2B);
  unsigned short* Hs  = (unsigned short*)(ws + WS_HS);
  unsigned short* Ys  = (unsigned short*)(ws + WS_YS);  // aliases Xbf+W1b

  // 5 launches total: router+transposes fused, prefix+scatter fused,
  // counts written non-atomically (no memset needed).
  k_fused<<<3*RBC, 256, 0, stream>>>(x, Wr, br, out, out + 65536, info,
                                     counts, Xbf, W1, W1b, W2, W2b);
  k_prefscatter<<<128, 256, 0, stream>>>(counts, info, tokl, slots2, offs, t1s);
  k_gemm1<<<17*128, 512, 0, stream>>>(Xbf, tokl, W1b, b1, Hs, offs, t1s);
  k_gemm2<<<17*32, 512, 0, stream>>>(Hs, W2b, b2, Ys, offs, t1s);
  k_combine<<<NTOK/4, 256, 0, stream>>>(Ys, info, slots2, out + 81920);
}

// Round 10
// 257.449 us; speedup vs baseline: 1.1621x; 1.0123x over previous
//
#include <hip/hip_runtime.h>
#include <hip/hip_bf16.h>

// Problem dims
#define NTOK 8192       // B*T
#define NASN 16384      // NTOK * K(=2)
#define C_ 512
#define H_ 2048
#define E_ 8
#define RBC 2048        // router blocks (4 tokens each) = count granularity
#define G1BLK 1088      // gemm1 compute blocks (17 m-groups x 64)

typedef __bf16 bf16x8 __attribute__((ext_vector_type(8)));
typedef float f32x4 __attribute__((ext_vector_type(4)));

// Workspace layout (bytes). Total ~109.5 MB.
#define WS_COUNTS 0                              // RBC*8*4 = 64 KB (written, not atomically)
#define WS_OFFS   65536                          // 9*4 -> pad 256
#define WS_T1S    65792                          // 9*4
#define WS_INFO   66048                          // NTOK*16
#define WS_TOKL   (WS_INFO + NTOK*16)            // NASN*4
#define WS_SLOTS  (WS_TOKL + NASN*4)             // NTOK*8 (int2)
#define WS_XBF    (WS_SLOTS + NTOK*8)            // NTOK*C_*2 bf16 token-ordered x
#define WS_W1B    (WS_XBF + (size_t)NTOK*C_*2)   // E*H*C bf16, [e][h][c]
#define WS_W2B    (WS_W1B + (size_t)E_*H_*C_*2)  // E*C*H bf16, [e][c][h]
#define WS_HS     (WS_W2B + (size_t)E_*H_*C_*2)  // NASN*H bf16 hidden acts
// Ys (bf16, NASN*C_*2 = 16.78 MB) aliases Xbf+W1b (25.2 MB, dead by k_gemm2).
#define WS_YS     WS_XBF

__device__ __forceinline__ unsigned int f2bf(float f) {
  __hip_bfloat16 h = __float2bfloat16(f);
  return (unsigned int)*(unsigned short*)&h;
}
__device__ __forceinline__ float bf2f(unsigned int u) {
  return __int_as_float((u & 0xffffu) << 16);
}

// async global->LDS, 16B per lane; LDS dest = wave-uniform base + lane*16
__device__ __forceinline__ void g2l16(const unsigned short* g, unsigned short* l) {
  __builtin_amdgcn_global_load_lds(
      (const __attribute__((address_space(1))) unsigned int*)g,
      (__attribute__((address_space(3))) unsigned int*)l, 16, 0, 0);
}

// Pair-interleaved XOR LDS layout for a [rows x 32 ushort] panel:
// 16B chunk of (row r, k-chunk q) at linear chunk (r>>1)*8 + slot,
// slot = ((r&1)*4 + q) ^ ((r>>1)&7).  Full 32-bank coverage on fragment reads.
__device__ __forceinline__ void stage_decode(int L, int& brow, int& q) {
  int s = L >> 3, slot = L & 7;
  int v = slot ^ (s & 7);
  brow = 2*s + (v >> 2);
  q = v & 3;
}

// ---------------- fused: router (b<2048) | W1 transpose ----------------
__global__ __launch_bounds__(256) void k_fused(
    const float* __restrict__ x, const float* __restrict__ Wr,
    const float* __restrict__ br, float* __restrict__ out_logits,
    float* __restrict__ out_idx, int4* __restrict__ info,
    int* __restrict__ counts, unsigned short* __restrict__ Xbf,
    const float* __restrict__ W1, unsigned short* __restrict__ W1b)
{
  __shared__ float tileS[128][33];
  __shared__ int bc[8];
  int b = blockIdx.x;
  int tid = threadIdx.x;

  if (b < RBC) {
    // ---- router: 4 tokens per block, one wave each; non-atomic counts ----
    if (tid < 8) bc[tid] = 0;
    __syncthreads();
    int t = b * 4 + (tid >> 6);
    int lane = tid & 63;
    const float4* xr = (const float4*)(x + (size_t)t * C_);
    float4 x0 = xr[lane*2], x1 = xr[lane*2+1];
    uint4 pk;
    pk.x = f2bf(x0.x) | (f2bf(x0.y) << 16);
    pk.y = f2bf(x0.z) | (f2bf(x0.w) << 16);
    pk.z = f2bf(x1.x) | (f2bf(x1.y) << 16);
    pk.w = f2bf(x1.z) | (f2bf(x1.w) << 16);
    *(uint4*)(Xbf + (size_t)t * C_ + lane*8) = pk;

    float xs[8] = {x0.x,x0.y,x0.z,x0.w,x1.x,x1.y,x1.z,x1.w};
    float acc[8] = {0,0,0,0,0,0,0,0};
    #pragma unroll
    for (int j = 0; j < 8; j++) {
      const float4* w = (const float4*)(Wr + (size_t)(lane*8+j) * E_);
      float4 w0 = w[0], w1 = w[1];
      float we[8] = {w0.x,w0.y,w0.z,w0.w,w1.x,w1.y,w1.z,w1.w};
      #pragma unroll
      for (int e = 0; e < 8; e++) acc[e] += xs[j] * we[e];
    }
    #pragma unroll
    for (int off = 1; off < 64; off <<= 1) {
      #pragma unroll
      for (int e = 0; e < 8; e++) acc[e] += __shfl_xor(acc[e], off, 64);
    }
    #pragma unroll
    for (int e = 0; e < 8; e++) acc[e] += br[e];
    if (lane == 0) {
      #pragma unroll
      for (int e = 0; e < 8; e++) out_logits[t*8 + e] = acc[e];
      int i0 = 0; float v0 = acc[0];
      #pragma unroll
      for (int e = 1; e < 8; e++) if (acc[e] > v0) { v0 = acc[e]; i0 = e; }
      int i1 = -1; float v1 = -1e30f;
      #pragma unroll
      for (int e = 0; e < 8; e++) if (e != i0 && acc[e] > v1) { v1 = acc[e]; i1 = e; }
      float d = expf(v1 - v0);
      float s1 = d / (1.0f + d);
      float s0 = 1.0f - s1;
      out_idx[t*2]     = (float)i0;
      out_idx[t*2 + 1] = (float)i1;
      info[t] = make_int4(i0, i1, __float_as_int(s0), __float_as_int(s1));
      atomicAdd(&bc[i0], 1);     // LDS atomic, block-local
      atomicAdd(&bc[i1], 1);
    }
    __syncthreads();
    if (tid < 8) counts[b*8 + tid] = bc[tid];   // full write: no memset needed
    return;
  }

  // ---- W1 transpose: fp32[C][H] -> bf16[H][C] ----
  int bb = b - RBC;
  const float* in = W1; unsigned short* outp = W1b;
  int R = C_, S = H_;
  int bx = bb & 63, by = (bb >> 6) & 3, bz = bb >> 8;
  size_t zo = (size_t)bz * R * S;
  in += zo; outp += zo;
  int r0 = by * 128, s0 = bx * 32;
  // float4 loads: 16B/lane
  #pragma unroll
  for (int i = 0; i < 4; i++) {
    int lin = i*256 + tid;               // 1024 = 128 rows x 8 quads
    int rr = lin >> 3, sq = lin & 7;
    float4 v = *(const float4*)(in + (size_t)(r0 + rr) * S + s0 + sq*4);
    tileS[rr][sq*4+0] = v.x;
    tileS[rr][sq*4+1] = v.y;
    tileS[rr][sq*4+2] = v.z;
    tileS[rr][sq*4+3] = v.w;
  }
  __syncthreads();
  #pragma unroll
  for (int i = 0; i < 4; i++) {
    int lin = i*256 + tid;
    int ss = lin >> 5, rq = lin & 31;
    ushort4 v;
    v.x = (unsigned short)f2bf(tileS[rq*4+0][ss]);
    v.y = (unsigned short)f2bf(tileS[rq*4+1][ss]);
    v.z = (unsigned short)f2bf(tileS[rq*4+2][ss]);
    v.w = (unsigned short)f2bf(tileS[rq*4+3][ss]);
    *(ushort4*)(outp + (size_t)(s0 + ss) * R + r0 + rq*4) = v;
  }
}

// ---------------- prefix+scatter fused: 128 blocks x 256 threads ----------------
__global__ __launch_bounds__(256) void k_prefscatter(
    const int* __restrict__ counts, const int4* __restrict__ info,
    int* __restrict__ tokl, int2* __restrict__ slots2,
    int* __restrict__ offs, int* __restrict__ t1s)
{
  __shared__ int full_s[8][32];
  __shared__ int part_s[8][32];
  __shared__ int tot_s[8];
  __shared__ int off_s[9];
  __shared__ int cur[8];
  int c = blockIdx.x, t = threadIdx.x;
  int e = t & 7, g = t >> 3;          // 8 experts x 32 groups of 64 router-blocks
  int lim = c * 16;                   // chunk c covers router blocks [0, c*16)
  int full = 0, part = 0;
  for (int i = 0; i < 64; i++) {
    int rb = g*64 + i;
    int v = counts[rb*8 + e];
    full += v;
    if (rb < lim) part += v;
  }
  full_s[e][g] = full; part_s[e][g] = part;
  __syncthreads();
  if (t < 8) {
    int s = 0;
    #pragma unroll
    for (int gg = 0; gg < 32; gg++) s += full_s[t][gg];
    tot_s[t] = s;
  }
  __syncthreads();
  if (t == 0) {
    int o = 0;
    off_s[0] = 0;
    for (int ee = 0; ee < 8; ee++) { o += tot_s[ee]; off_s[ee+1] = o; }
    if (c == 0) {
      offs[0] = 0; t1s[0] = 0;
      int tt = 0;
      for (int ee = 0; ee < 8; ee++) {
        offs[ee+1] = off_s[ee+1];
        tt += (tot_s[ee] + 127) >> 7;
        t1s[ee+1] = tt;
      }
    }
  }
  __syncthreads();
  if (t < 8) {
    int mg = c >> 2;                  // lim/64
    int bse = off_s[t];
    #pragma unroll
    for (int gg = 0; gg < 32; gg++) if (gg < mg) bse += full_s[t][gg];
    bse += part_s[t][mg];
    cur[t] = bse;
  }
  __syncthreads();
  if (t < 64) {
    int tok = c*64 + t;
    int4 nfo = info[tok];
    int r0 = atomicAdd(&cur[nfo.x], 1);
    int r1 = atomicAdd(&cur[nfo.y], 1);
    tokl[r0] = tok;
    tokl[r1] = tok;
    slots2[tok] = make_int2(r0, r1);
  }
}

// ---------------- gemm1 (128x256 tile) + W2-transpose overlap ----------------
// gemm1: BK=32, 8 waves, wave grid 2M x 4N, wave tile 64x64 (acc 4x4):
// 8 ds_read_b128 per 16 MFMA per wave (ratio 0.5 vs 0.75 at 128x128).
// 72KB LDS tri-buffer (A 8KB + B 16KB per buf) -> 2 blocks/CU = 16 waves/CU.
// 1 barrier/K-step, counted vmcnt(3) (1 A + 2 B chunks staged per wave/step),
// setprio clusters, pair-interleaved XOR LDS.
// Blocks >= G1BLK run the W2 transpose (independent of gemm1; must finish
// before k_gemm2, which this launch boundary guarantees).
__global__ __launch_bounds__(512) void k_gemm1(
    const unsigned short* __restrict__ Xbf, const int* __restrict__ tokl,
    const unsigned short* __restrict__ W1b,
    const float* __restrict__ b1, unsigned short* __restrict__ Hs,
    const int* __restrict__ offs, const int* __restrict__ t1s,
    const float* __restrict__ W2, unsigned short* __restrict__ W2b)
{
  __shared__ __align__(16) unsigned short AB[3*12288];   // 72 KB
  int b = blockIdx.x;
  int tid = threadIdx.x;

  if (b >= G1BLK) {
    // ---- W2 transpose: fp32[H][C] -> bf16[C][H], 128x64 tile, 512 thr ----
    float* tS = (float*)AB;              // [128][65] floats = 33.3 KB
    int b2 = b - G1BLK;                  // 8 x 16 x 8 = 1024 blocks
    int bx = b2 & 7, by = (b2 >> 3) & 15, bz = b2 >> 7;
    const float* in = W2 + (size_t)bz * H_ * C_;
    unsigned short* outp = W2b + (size_t)bz * H_ * C_;
    int r0 = by * 128, s0 = bx * 64;
    #pragma unroll
    for (int i = 0; i < 4; i++) {
      int lin = i*512 + tid;             // 2048 = 128 rows x 16 quads
      int rr = lin >> 4, cq = lin & 15;
      float4 v = *(const float4*)(in + (size_t)(r0 + rr) * C_ + s0 + cq*4);
      tS[rr*65 + cq*4+0] = v.x;
      tS[rr*65 + cq*4+1] = v.y;
      tS[rr*65 + cq*4+2] = v.z;
      tS[rr*65 + cq*4+3] = v.w;
    }
    __syncthreads();
    #pragma unroll
    for (int i = 0; i < 4; i++) {
      int lin = i*512 + tid;             // 2048 = 64 cols x 32 row-quads
      int ss = lin >> 5, rq = lin & 31;
      ushort4 v;
      v.x = (unsigned short)f2bf(tS[(rq*4+0)*65 + ss]);
      v.y = (unsigned short)f2bf(tS[(rq*4+1)*65 + ss]);
      v.z = (unsigned short)f2bf(tS[(rq*4+2)*65 + ss]);
      v.w = (unsigned short)f2bf(tS[(rq*4+3)*65 + ss]);
      *(ushort4*)(outp + (size_t)(s0 + ss) * H_ + r0 + rq*4) = v;
    }
    return;
  }

  // ---- gemm1 compute ----
  int mo = b >> 6, rr = b & 63;
  int n0 = (rr >> 3) * 256;
  int mt = mo*8 + (rr & 7);              // same-A blocks congruent mod 8 (XCD)
  if (mt >= t1s[8]) return;
  int e = 0;
  #pragma unroll
  for (int i = 0; i < 7; i++) if (mt >= t1s[i+1]) e++;
  int row0 = offs[e] + (mt - t1s[e]) * 128;
  int rowEnd = offs[e+1];
  int lane = tid & 63, w = tid >> 6;
  int wm = (w >> 2) * 64, wn = (w & 3) * 64;
  int quad = lane >> 4, l16 = lane & 15;
  const f32x4 zero = {0.f, 0.f, 0.f, 0.f};
  f32x4 acc[4][4];
  #pragma unroll
  for (int i = 0; i < 4; i++)
    #pragma unroll
    for (int j = 0; j < 4; j++) acc[i][j] = zero;
  const unsigned short* Bsrc = W1b + ((size_t)e * H_ + n0) * C_;

  // staging: wave w stages 1 A-chunk (L=w*64+lane over 128x32) and
  // 2 B-chunks (L=(w*2+j)*64+lane over 256x32)
  const unsigned short* ga; int lao;
  const unsigned short* gb[2]; int lbo[2];
  {
    int L = w*64 + lane;
    int brow, q; stage_decode(L, brow, q);
    int gr = row0 + brow; gr = gr < NASN-1 ? gr : NASN-1;
    int trow = tokl[gr];
    ga = Xbf + (size_t)trow * C_ + q*8;
    lao = w*512;
  }
  #pragma unroll
  for (int j = 0; j < 2; j++) {
    int L = (w*2 + j)*64 + lane;
    int brow, q; stage_decode(L, brow, q);
    gb[j] = Bsrc + (size_t)brow * C_ + q*8;
    lbo[j] = 4096 + (w*2 + j)*512;
  }
  int rbase = (l16>>1)*64 + ((((l16&1)<<2) + quad) ^ (l16>>1))*8;
  const int KI = C_ / 32;   // 16

  // prologue: tiles 0,1 -> buffers 0,1 (3 issues each per wave)
  g2l16(ga, AB + lao);
  g2l16(gb[0], AB + lbo[0]); g2l16(gb[1], AB + lbo[1]);
  g2l16(ga + 32, AB + 12288 + lao);
  g2l16(gb[0] + 32, AB + 12288 + lbo[0]); g2l16(gb[1] + 32, AB + 12288 + lbo[1]);

  {
    int cOff = 0, sOff = 2*12288;
    for (int ki = 0; ki < KI; ki++) {
      if (ki + 1 < KI)
        asm volatile("s_waitcnt vmcnt(3)" ::: "memory");
      else
        asm volatile("s_waitcnt vmcnt(0)" ::: "memory");
      asm volatile("s_barrier" ::: "memory");
      if (ki + 2 < KI) {
        int off_ = (ki + 2) * 32;
        unsigned short* nb_ = AB + sOff;
        g2l16(ga + off_, nb_ + lao);
        g2l16(gb[0] + off_, nb_ + lbo[0]);
        g2l16(gb[1] + off_, nb_ + lbo[1]);
      }
      const unsigned short* Ap_ = AB + cOff;
      const unsigned short* Bp_ = Ap_ + 4096;
      bf16x8 af_[4], bf_[4];
      #pragma unroll
      for (int i = 0; i < 4; i++)
        af_[i] = *(const bf16x8*)&Ap_[wm*32 + i*512 + rbase];
      #pragma unroll
      for (int j = 0; j < 4; j++)
        bf_[j] = *(const bf16x8*)&Bp_[wn*32 + j*512 + rbase];
      __builtin_amdgcn_s_setprio(1);
      #pragma unroll
      for (int i = 0; i < 4; i++)
        #pragma unroll
        for (int j = 0; j < 2; j++)
          acc[i][j] = __builtin_amdgcn_mfma_f32_16x16x32_bf16(af_[i], bf_[j], acc[i][j], 0, 0, 0);
      __builtin_amdgcn_s_setprio(0);
      __builtin_amdgcn_s_setprio(1);
      #pragma unroll
      for (int i = 0; i < 4; i++)
        #pragma unroll
        for (int j = 2; j < 4; j++)
          acc[i][j] = __builtin_amdgcn_mfma_f32_16x16x32_bf16(af_[i], bf_[j], acc[i][j], 0, 0, 0);
      __builtin_amdgcn_s_setprio(0);
      asm volatile("s_waitcnt lgkmcnt(0)" ::: "memory");
      cOff += 12288; if (cOff == 3*12288) cOff = 0;
      sOff += 12288; if (sOff == 3*12288) sOff = 0;
    }
  }
  __syncthreads();   // drain all waves' last-buffer reads before Lt overwrite

  // epilogue: per-wave LDS transpose (64x64, 8KB/wave) -> coalesced 16B stores
  unsigned short* Lt = AB + w*4096;
  #pragma unroll
  for (int j = 0; j < 4; j++) {
    int n = n0 + wn + j*16 + l16;
    float bias = b1[e * H_ + n];
    #pragma unroll
    for (int i = 0; i < 4; i++)
      #pragma unroll
      for (int r = 0; r < 4; r++) {
        float v = acc[i][j][r] + bias;
        Lt[(i*16 + quad*4 + r)*64 + j*16 + l16] = (unsigned short)f2bf(v > 0.f ? v : 0.f);
      }
  }
  #pragma unroll
  for (int it = 0; it < 8; it++) {
    int rloc = it*8 + (lane >> 3);
    int m = row0 + wm + rloc;
    uint4 vv = *(uint4*)&Lt[rloc*64 + (lane & 7)*8];
    if (m < rowEnd)
      *(uint4*)(Hs + (size_t)m * H_ + n0 + wn + (lane & 7)*8) = vv;
  }
}

// Inner K-loop for gemm2 (R5/R9 structure, measured 61.2-61.4us): 8 waves,
// wave tile 64x32, tri-buffered LDS, ONE barrier per K-step, counted
// vmcnt(2), stage-after-barrier, 2 setprio MFMA clusters.
#define KLOOP(KI)                                                              \
  {                                                                            \
    int cOff = 0, sOff = 2*8192;                                               \
    for (int ki = 0; ki < (KI); ki++) {                                        \
      if (ki + 1 < (KI))                                                       \
        asm volatile("s_waitcnt vmcnt(2)" ::: "memory");                       \
      else                                                                     \
        asm volatile("s_waitcnt vmcnt(0)" ::: "memory");                       \
      asm volatile("s_barrier" ::: "memory");                                  \
      if (ki + 2 < (KI)) {                                                     \
        int off_ = (ki + 2) * 32;                                              \
        unsigned short* nb_ = AB + sOff;                                       \
        g2l16(ga + off_, nb_ + lao);                                           \
        g2l16(gb + off_, nb_ + lbo);                                           \
      }                                                                        \
      const unsigned short* Ap_ = AB + cOff;                                   \
      const unsigned short* Bp_ = Ap_ + 4096;                                  \
      bf16x8 af0 = *(const bf16x8*)&Ap_[wm*32 + 0*512 + rbase];                \
      bf16x8 af1 = *(const bf16x8*)&Ap_[wm*32 + 1*512 + rbase];                \
      bf16x8 bf0 = *(const bf16x8*)&Bp_[wn*32 + 0*512 + rbase];                \
      bf16x8 bf1 = *(const bf16x8*)&Bp_[wn*32 + 1*512 + rbase];                \
      __builtin_amdgcn_s_setprio(1);                                           \
      acc[0][0] = __builtin_amdgcn_mfma_f32_16x16x32_bf16(af0, bf0, acc[0][0], 0, 0, 0); \
      acc[0][1] = __builtin_amdgcn_mfma_f32_16x16x32_bf16(af0, bf1, acc[0][1], 0, 0, 0); \
      acc[1][0] = __builtin_amdgcn_mfma_f32_16x16x32_bf16(af1, bf0, acc[1][0], 0, 0, 0); \
      acc[1][1] = __builtin_amdgcn_mfma_f32_16x16x32_bf16(af1, bf1, acc[1][1], 0, 0, 0); \
      __builtin_amdgcn_s_setprio(0);                                           \
      bf16x8 af2 = *(const bf16x8*)&Ap_[wm*32 + 2*512 + rbase];                \
      bf16x8 af3 = *(const bf16x8*)&Ap_[wm*32 + 3*512 + rbase];                \
      __builtin_amdgcn_s_setprio(1);                                           \
      acc[2][0] = __builtin_amdgcn_mfma_f32_16x16x32_bf16(af2, bf0, acc[2][0], 0, 0, 0); \
      acc[2][1] = __builtin_amdgcn_mfma_f32_16x16x32_bf16(af2, bf1, acc[2][1], 0, 0, 0); \
      acc[3][0] = __builtin_amdgcn_mfma_f32_16x16x32_bf16(af3, bf0, acc[3][0], 0, 0, 0); \
      acc[3][1] = __builtin_amdgcn_mfma_f32_16x16x32_bf16(af3, bf1, acc[3][1], 0, 0, 0); \
      __builtin_amdgcn_s_setprio(0);                                           \
      asm volatile("s_waitcnt lgkmcnt(0)" ::: "memory");                       \
      cOff += 8192; if (cOff == 3*8192) cOff = 0;                              \
      sOff += 8192; if (sOff == 3*8192) sOff = 0;                              \
    }                                                                          \
  }

// ---------------- grouped GEMM layer 2: Ys(bf16) = Hs @ W2 + b2 ----------------
// 128x128 tile, 8 waves, KI=64.  STATIC grid (XCD-affine).  Unchanged (control).
__global__ __launch_bounds__(512) void k_gemm2(
    const unsigned short* __restrict__ Hs, const unsigned short* __restrict__ W2b,
    const float* __restrict__ b2, unsigned short* __restrict__ Ys,
    const int* __restrict__ offs, const int* __restrict__ t1s)
{
  __shared__ __align__(16) unsigned short AB[3*8192];   // 48 KB
  int b = blockIdx.x;
  int mo = b >> 5, rr = b & 31;
  int n0 = (rr >> 3) * 128;
  int mt = mo*8 + (rr & 7);
  if (mt >= t1s[8]) return;
  int e = 0;
  #pragma unroll
  for (int i = 0; i < 7; i++) if (mt >= t1s[e+1]) e++;
  int row0 = offs[e] + (mt - t1s[e]) * 128;
  int rowEnd = offs[e+1];
  int tid = threadIdx.x, lane = tid & 63, w = tid >> 6;
  int wm = (w >> 2) * 64, wn = (w & 3) * 32;
  int quad = lane >> 4, l16 = lane & 15;
  const f32x4 zero = {0.f, 0.f, 0.f, 0.f};
  f32x4 acc[4][2];
  #pragma unroll
  for (int i = 0; i < 4; i++)
    #pragma unroll
    for (int j = 0; j < 2; j++) acc[i][j] = zero;
  const unsigned short* Bsrc = W2b + ((size_t)e * C_ + n0) * H_;

  const unsigned short* ga; const unsigned short* gb;
  int lao, lbo;
  {
    int L = w*64 + lane;
    int brow, q; stage_decode(L, brow, q);
    int gr = row0 + brow; gr = gr < NASN-1 ? gr : NASN-1;
    ga = Hs + (size_t)gr * H_ + q*8;
    gb = Bsrc + (size_t)brow * H_ + q*8;
    lao = w*512;
    lbo = 4096 + w*512;
  }
  int rbase = (l16>>1)*64 + ((((l16&1)<<2) + quad) ^ (l16>>1))*8;
  const int KI = H_ / 32;   // 64

  g2l16(ga, AB + lao);            g2l16(gb, AB + lbo);
  g2l16(ga + 32, AB + 8192 + lao); g2l16(gb + 32, AB + 8192 + lbo);

  KLOOP(KI);
  __syncthreads();   // drain all waves' last-buffer reads before Lt overwrite

  // epilogue: per-wave LDS transpose (64x32, 4KB/wave) -> coalesced bf16 stores
  unsigned short* Lt = AB + w*2048;
  #pragma unroll
  for (int j = 0; j < 2; j++) {
    int n = n0 + wn + j*16 + l16;
    float bias = b2[e * C_ + n];
    #pragma unroll
    for (int i = 0; i < 4; i++)
      #pragma unroll
      for (int r = 0; r < 4; r++)
        Lt[(i*16 + quad*4 + r)*32 + j*16 + l16] =
            (unsigned short)f2bf(acc[i][j][r] + bias);
  }
  #pragma unroll
  for (int it = 0; it < 4; it++) {
    int rloc = it*16 + (lane >> 2);
    int m = row0 + wm + rloc;
    uint4 vv = *(uint4*)&Lt[rloc*32 + (lane & 3)*8];
    if (m < rowEnd)
      *(uint4*)(Ys + (size_t)m * C_ + n0 + wn + (lane & 3)*8) = vv;
  }
}

// ---------------- combine: out[t] = g0*Ys[s0] + g1*Ys[s1] (bf16 Ys) ----------------
__global__ __launch_bounds__(256) void k_combine(
    const unsigned short* __restrict__ Ys, const int4* __restrict__ info,
    const int2* __restrict__ slots2, float* __restrict__ outp)
{
  int t = blockIdx.x * 4 + (threadIdx.x >> 6);
  int lane = threadIdx.x & 63;
  int4 nfo = info[t];
  int2 ss = slots2[t];
  float g0 = __int_as_float(nfo.z), g1 = __int_as_float(nfo.w);
  uint4 a = *(const uint4*)(Ys + (size_t)ss.x * C_ + lane*8);
  uint4 bb = *(const uint4*)(Ys + (size_t)ss.y * C_ + lane*8);
  unsigned int au[4] = {a.x, a.y, a.z, a.w};
  unsigned int bu[4] = {bb.x, bb.y, bb.z, bb.w};
  float vals[8];
  #pragma unroll
  for (int q = 0; q < 4; q++) {
    vals[q*2]   = g0*bf2f(au[q])       + g1*bf2f(bu[q]);
    vals[q*2+1] = g0*bf2f(au[q] >> 16) + g1*bf2f(bu[q] >> 16);
  }
  float4 o0, o1;
  o0.x = vals[0]; o0.y = vals[1]; o0.z = vals[2]; o0.w = vals[3];
  o1.x = vals[4]; o1.y = vals[5]; o1.z = vals[6]; o1.w = vals[7];
  float4* o = (float4*)(outp + (size_t)t * C_ + lane*8);
  o[0] = o0;
  o[1] = o1;
}

extern "C" void kernel_launch(void* const* d_in, const int* in_sizes, int n_in,
                              void* d_out, int out_size, void* d_ws, size_t ws_size,
                              hipStream_t stream)
{
  const float* x  = (const float*)d_in[0];
  const float* Wr = (const float*)d_in[1];
  const float* br = (const float*)d_in[2];
  const float* W1 = (const float*)d_in[3];
  const float* b1 = (const float*)d_in[4];
  const float* W2 = (const float*)d_in[5];
  const float* b2 = (const float*)d_in[6];
  float* out = (float*)d_out;   // [logits 65536 | idx 16384 | out 4194304]
  char* ws = (char*)d_ws;

  int*  counts = (int*)(ws + WS_COUNTS);
  int*  offs   = (int*)(ws + WS_OFFS);
  int*  t1s    = (int*)(ws + WS_T1S);
  int4* info   = (int4*)(ws + WS_INFO);
  int*  tokl   = (int*)(ws + WS_TOKL);
  int2* slots2 = (int2*)(ws + WS_SLOTS);
  unsigned short* Xbf = (unsigned short*)(ws + WS_XBF);
  unsigned short* W1b = (unsigned short*)(ws + WS_W1B);
  unsigned short* W2b = (unsigned short*)(ws + WS_W2B);
  unsigned short* Hs  = (unsigned short*)(ws + WS_HS);
  unsigned short* Ys  = (unsigned short*)(ws + WS_YS);  // aliases Xbf+W1b

  // 5 launches: router+W1T fused, prefix+scatter, gemm1(128x256)+W2T overlap,
  // gemm2 (unchanged control), combine.
  k_fused<<<2*RBC, 256, 0, stream>>>(x, Wr, br, out, out + 65536, info,
                                     counts, Xbf, W1, W1b);
  k_prefscatter<<<128, 256, 0, stream>>>(counts, info, tokl, slots2, offs, t1s);
  k_gemm1<<<G1BLK + 1024, 512, 0, stream>>>(Xbf, tokl, W1b, b1, Hs, offs, t1s,
                                            W2, W2b);
  k_gemm2<<<17*32, 512, 0, stream>>>(Hs, W2b, b2, Ys, offs, t1s);
  k_combine<<<NTOK/4, 256, 0, stream>>>(Ys, info, slots2, out + 81920);
}

// Round 11
// 243.419 us; speedup vs baseline: 1.2291x; 1.0576x over previous
//
#include <hip/hip_runtime.h>
#include <hip/hip_bf16.h>

// Problem dims
#define NTOK 8192       // B*T
#define NASN 16384      // NTOK * K(=2)
#define C_ 512
#define H_ 2048
#define E_ 8
#define RBC 2048        // router blocks (4 tokens each) = count granularity
#define G1BLK 1088      // gemm1 compute blocks (17 m-groups x 64)

typedef __bf16 bf16x8 __attribute__((ext_vector_type(8)));
typedef float f32x4 __attribute__((ext_vector_type(4)));

// Workspace layout (bytes). Total ~109.5 MB.
#define WS_COUNTS 0                              // RBC*8*4 = 64 KB (written, not atomically)
#define WS_OFFS   65536                          // 9*4 -> pad 256
#define WS_T1S    65792                          // 9*4
#define WS_INFO   66048                          // NTOK*16
#define WS_TOKL   (WS_INFO + NTOK*16)            // NASN*4
#define WS_SLOTS  (WS_TOKL + NASN*4)             // NTOK*8 (int2)
#define WS_XBF    (WS_SLOTS + NTOK*8)            // NTOK*C_*2 bf16 token-ordered x
#define WS_W1B    (WS_XBF + (size_t)NTOK*C_*2)   // E*H*C bf16, [e][h][c]
#define WS_W2B    (WS_W1B + (size_t)E_*H_*C_*2)  // E*C*H bf16, [e][c][h]
#define WS_HS     (WS_W2B + (size_t)E_*H_*C_*2)  // NASN*H bf16 hidden acts
// Ys (bf16, NASN*C_*2 = 16.78 MB) aliases Xbf+W1b (25.2 MB, dead by k_gemm2).
#define WS_YS     WS_XBF

__device__ __forceinline__ unsigned int f2bf(float f) {
  __hip_bfloat16 h = __float2bfloat16(f);
  return (unsigned int)*(unsigned short*)&h;
}
__device__ __forceinline__ float bf2f(unsigned int u) {
  return __int_as_float((u & 0xffffu) << 16);
}

// async global->LDS, 16B per lane; LDS dest = wave-uniform base + lane*16
__device__ __forceinline__ void g2l16(const unsigned short* g, unsigned short* l) {
  __builtin_amdgcn_global_load_lds(
      (const __attribute__((address_space(1))) unsigned int*)g,
      (__attribute__((address_space(3))) unsigned int*)l, 16, 0, 0);
}

// Pair-interleaved XOR LDS layout for a [rows x 32 ushort] panel:
// 16B chunk of (row r, k-chunk q) at linear chunk (r>>1)*8 + slot,
// slot = ((r&1)*4 + q) ^ ((r>>1)&7).  Full 32-bank coverage on fragment reads.
__device__ __forceinline__ void stage_decode(int L, int& brow, int& q) {
  int s = L >> 3, slot = L & 7;
  int v = slot ^ (s & 7);
  brow = 2*s + (v >> 2);
  q = v & 3;
}

// ---------------- fused: router (b<2048) | W1 transpose ----------------
__global__ __launch_bounds__(256) void k_fused(
    const float* __restrict__ x, const float* __restrict__ Wr,
    const float* __restrict__ br, float* __restrict__ out_logits,
    float* __restrict__ out_idx, int4* __restrict__ info,
    int* __restrict__ counts, unsigned short* __restrict__ Xbf,
    const float* __restrict__ W1, unsigned short* __restrict__ W1b)
{
  __shared__ float tileS[128][33];     // 16.9 KB; router overlays it as wls
  __shared__ int bc[8];
  int b = blockIdx.x;
  int tid = threadIdx.x;

  if (b < RBC) {
    // ---- router: 4 tokens per block, one wave each; non-atomic counts ----
    // Wr staged in LDS, chunk layout: chunk i (rows 8i..8i+7 = 64 dwords) at
    // dword offset i*65.  Global load fully coalesced; lane reads hit bank
    // (lane+s)%32 -> 2 lanes/bank (free).  Replaces 256B-stride uncoalesced
    // global Wr reads (64 distinct lines per instruction).
    float* wls = (float*)tileS;        // 64*65*4 = 16.6 KB <= tileS
    if (tid < 8) bc[tid] = 0;
    #pragma unroll
    for (int it = 0; it < 4; it++) {
      int g = it*1024 + tid*4;         // dword index into Wr (4096 dwords)
      float4 v = *(const float4*)(Wr + g);
      int ch = g >> 6, off = g & 63;
      float* d = wls + ch*65 + off;
      d[0] = v.x; d[1] = v.y; d[2] = v.z; d[3] = v.w;
    }
    __syncthreads();
    int t = b * 4 + (tid >> 6);
    int lane = tid & 63;
    const float4* xr = (const float4*)(x + (size_t)t * C_);
    float4 x0 = xr[lane*2], x1 = xr[lane*2+1];
    uint4 pk;
    pk.x = f2bf(x0.x) | (f2bf(x0.y) << 16);
    pk.y = f2bf(x0.z) | (f2bf(x0.w) << 16);
    pk.z = f2bf(x1.x) | (f2bf(x1.y) << 16);
    pk.w = f2bf(x1.z) | (f2bf(x1.w) << 16);
    *(uint4*)(Xbf + (size_t)t * C_ + lane*8) = pk;

    float xs[8] = {x0.x,x0.y,x0.z,x0.w,x1.x,x1.y,x1.z,x1.w};
    float acc[8] = {0,0,0,0,0,0,0,0};
    const float* wch = wls + lane*65;  // this lane's 8 rows (row-major [8][8])
    #pragma unroll
    for (int j = 0; j < 8; j++) {
      #pragma unroll
      for (int e = 0; e < 8; e++) acc[e] += xs[j] * wch[j*8 + e];
    }
    #pragma unroll
    for (int off = 1; off < 64; off <<= 1) {
      #pragma unroll
      for (int e = 0; e < 8; e++) acc[e] += __shfl_xor(acc[e], off, 64);
    }
    #pragma unroll
    for (int e = 0; e < 8; e++) acc[e] += br[e];
    if (lane == 0) {
      #pragma unroll
      for (int e = 0; e < 8; e++) out_logits[t*8 + e] = acc[e];
      int i0 = 0; float v0 = acc[0];
      #pragma unroll
      for (int e = 1; e < 8; e++) if (acc[e] > v0) { v0 = acc[e]; i0 = e; }
      int i1 = -1; float v1 = -1e30f;
      #pragma unroll
      for (int e = 0; e < 8; e++) if (e != i0 && acc[e] > v1) { v1 = acc[e]; i1 = e; }
      float d = expf(v1 - v0);
      float s1 = d / (1.0f + d);
      float s0 = 1.0f - s1;
      out_idx[t*2]     = (float)i0;
      out_idx[t*2 + 1] = (float)i1;
      info[t] = make_int4(i0, i1, __float_as_int(s0), __float_as_int(s1));
      atomicAdd(&bc[i0], 1);     // LDS atomic, block-local
      atomicAdd(&bc[i1], 1);
    }
    __syncthreads();
    if (tid < 8) counts[b*8 + tid] = bc[tid];   // full write: no memset needed
    return;
  }

  // ---- W1 transpose: fp32[C][H] -> bf16[H][C] ----
  int bb = b - RBC;
  const float* in = W1; unsigned short* outp = W1b;
  int R = C_, S = H_;
  int bx = bb & 63, by = (bb >> 6) & 3, bz = bb >> 8;
  size_t zo = (size_t)bz * R * S;
  in += zo; outp += zo;
  int r0 = by * 128, s0 = bx * 32;
  // float4 loads: 16B/lane
  #pragma unroll
  for (int i = 0; i < 4; i++) {
    int lin = i*256 + tid;               // 1024 = 128 rows x 8 quads
    int rr = lin >> 3, sq = lin & 7;
    float4 v = *(const float4*)(in + (size_t)(r0 + rr) * S + s0 + sq*4);
    tileS[rr][sq*4+0] = v.x;
    tileS[rr][sq*4+1] = v.y;
    tileS[rr][sq*4+2] = v.z;
    tileS[rr][sq*4+3] = v.w;
  }
  __syncthreads();
  #pragma unroll
  for (int i = 0; i < 4; i++) {
    int lin = i*256 + tid;
    int ss = lin >> 5, rq = lin & 31;
    ushort4 v;
    v.x = (unsigned short)f2bf(tileS[rq*4+0][ss]);
    v.y = (unsigned short)f2bf(tileS[rq*4+1][ss]);
    v.z = (unsigned short)f2bf(tileS[rq*4+2][ss]);
    v.w = (unsigned short)f2bf(tileS[rq*4+3][ss]);
    *(ushort4*)(outp + (size_t)(s0 + ss) * R + r0 + rq*4) = v;
  }
}

// ---------------- prefix+scatter fused: 128 blocks x 256 threads ----------------
__global__ __launch_bounds__(256) void k_prefscatter(
    const int* __restrict__ counts, const int4* __restrict__ info,
    int* __restrict__ tokl, int2* __restrict__ slots2,
    int* __restrict__ offs, int* __restrict__ t1s)
{
  __shared__ int full_s[8][32];
  __shared__ int part_s[8][32];
  __shared__ int tot_s[8];
  __shared__ int off_s[9];
  __shared__ int cur[8];
  int c = blockIdx.x, t = threadIdx.x;
  int e = t & 7, g = t >> 3;          // 8 experts x 32 groups of 64 router-blocks
  int lim = c * 16;                   // chunk c covers router blocks [0, c*16)
  int full = 0, part = 0;
  for (int i = 0; i < 64; i++) {
    int rb = g*64 + i;
    int v = counts[rb*8 + e];
    full += v;
    if (rb < lim) part += v;
  }
  full_s[e][g] = full; part_s[e][g] = part;
  __syncthreads();
  if (t < 8) {
    int s = 0;
    #pragma unroll
    for (int gg = 0; gg < 32; gg++) s += full_s[t][gg];
    tot_s[t] = s;
  }
  __syncthreads();
  if (t == 0) {
    int o = 0;
    off_s[0] = 0;
    for (int ee = 0; ee < 8; ee++) { o += tot_s[ee]; off_s[ee+1] = o; }
    if (c == 0) {
      offs[0] = 0; t1s[0] = 0;
      int tt = 0;
      for (int ee = 0; ee < 8; ee++) {
        offs[ee+1] = off_s[ee+1];
        tt += (tot_s[ee] + 127) >> 7;
        t1s[ee+1] = tt;
      }
    }
  }
  __syncthreads();
  if (t < 8) {
    int mg = c >> 2;                  // lim/64
    int bse = off_s[t];
    #pragma unroll
    for (int gg = 0; gg < 32; gg++) if (gg < mg) bse += full_s[t][gg];
    bse += part_s[t][mg];
    cur[t] = bse;
  }
  __syncthreads();
  if (t < 64) {
    int tok = c*64 + t;
    int4 nfo = info[tok];
    int r0 = atomicAdd(&cur[nfo.x], 1);
    int r1 = atomicAdd(&cur[nfo.y], 1);
    tokl[r0] = tok;
    tokl[r1] = tok;
    slots2[tok] = make_int2(r0, r1);
  }
}

// ---------------- gemm1 (128x256 tile) + W2-transpose overlap ----------------
__global__ __launch_bounds__(512) void k_gemm1(
    const unsigned short* __restrict__ Xbf, const int* __restrict__ tokl,
    const unsigned short* __restrict__ W1b,
    const float* __restrict__ b1, unsigned short* __restrict__ Hs,
    const int* __restrict__ offs, const int* __restrict__ t1s,
    const float* __restrict__ W2, unsigned short* __restrict__ W2b)
{
  __shared__ __align__(16) unsigned short AB[3*12288];   // 72 KB
  int b = blockIdx.x;
  int tid = threadIdx.x;

  if (b >= G1BLK) {
    // ---- W2 transpose: fp32[H][C] -> bf16[C][H], 128x64 tile, 512 thr ----
    float* tS = (float*)AB;              // [128][65] floats = 33.3 KB
    int b2 = b - G1BLK;                  // 8 x 16 x 8 = 1024 blocks
    int bx = b2 & 7, by = (b2 >> 3) & 15, bz = b2 >> 7;
    const float* in = W2 + (size_t)bz * H_ * C_;
    unsigned short* outp = W2b + (size_t)bz * H_ * C_;
    int r0 = by * 128, s0 = bx * 64;
    #pragma unroll
    for (int i = 0; i < 4; i++) {
      int lin = i*512 + tid;             // 2048 = 128 rows x 16 quads
      int rr = lin >> 4, cq = lin & 15;
      float4 v = *(const float4*)(in + (size_t)(r0 + rr) * C_ + s0 + cq*4);
      tS[rr*65 + cq*4+0] = v.x;
      tS[rr*65 + cq*4+1] = v.y;
      tS[rr*65 + cq*4+2] = v.z;
      tS[rr*65 + cq*4+3] = v.w;
    }
    __syncthreads();
    #pragma unroll
    for (int i = 0; i < 4; i++) {
      int lin = i*512 + tid;             // 2048 = 64 cols x 32 row-quads
      int ss = lin >> 5, rq = lin & 31;
      ushort4 v;
      v.x = (unsigned short)f2bf(tS[(rq*4+0)*65 + ss]);
      v.y = (unsigned short)f2bf(tS[(rq*4+1)*65 + ss]);
      v.z = (unsigned short)f2bf(tS[(rq*4+2)*65 + ss]);
      v.w = (unsigned short)f2bf(tS[(rq*4+3)*65 + ss]);
      *(ushort4*)(outp + (size_t)(s0 + ss) * H_ + r0 + rq*4) = v;
    }
    return;
  }

  // ---- gemm1 compute: BK=32, 8 waves, wave tile 64x64 (acc 4x4) ----
  int mo = b >> 6, rr = b & 63;
  int n0 = (rr >> 3) * 256;
  int mt = mo*8 + (rr & 7);              // same-A blocks congruent mod 8 (XCD)
  if (mt >= t1s[8]) return;
  int e = 0;
  #pragma unroll
  for (int i = 0; i < 7; i++) if (mt >= t1s[i+1]) e++;
  int row0 = offs[e] + (mt - t1s[e]) * 128;
  int rowEnd = offs[e+1];
  int lane = tid & 63, w = tid >> 6;
  int wm = (w >> 2) * 64, wn = (w & 3) * 64;
  int quad = lane >> 4, l16 = lane & 15;
  const f32x4 zero = {0.f, 0.f, 0.f, 0.f};
  f32x4 acc[4][4];
  #pragma unroll
  for (int i = 0; i < 4; i++)
    #pragma unroll
    for (int j = 0; j < 4; j++) acc[i][j] = zero;
  const unsigned short* Bsrc = W1b + ((size_t)e * H_ + n0) * C_;

  const unsigned short* ga; int lao;
  const unsigned short* gb[2]; int lbo[2];
  {
    int L = w*64 + lane;
    int brow, q; stage_decode(L, brow, q);
    int gr = row0 + brow; gr = gr < NASN-1 ? gr : NASN-1;
    int trow = tokl[gr];
    ga = Xbf + (size_t)trow * C_ + q*8;
    lao = w*512;
  }
  #pragma unroll
  for (int j = 0; j < 2; j++) {
    int L = (w*2 + j)*64 + lane;
    int brow, q; stage_decode(L, brow, q);
    gb[j] = Bsrc + (size_t)brow * C_ + q*8;
    lbo[j] = 4096 + (w*2 + j)*512;
  }
  int rbase = (l16>>1)*64 + ((((l16&1)<<2) + quad) ^ (l16>>1))*8;
  const int KI = C_ / 32;   // 16

  g2l16(ga, AB + lao);
  g2l16(gb[0], AB + lbo[0]); g2l16(gb[1], AB + lbo[1]);
  g2l16(ga + 32, AB + 12288 + lao);
  g2l16(gb[0] + 32, AB + 12288 + lbo[0]); g2l16(gb[1] + 32, AB + 12288 + lbo[1]);

  {
    int cOff = 0, sOff = 2*12288;
    for (int ki = 0; ki < KI; ki++) {
      if (ki + 1 < KI)
        asm volatile("s_waitcnt vmcnt(3)" ::: "memory");
      else
        asm volatile("s_waitcnt vmcnt(0)" ::: "memory");
      asm volatile("s_barrier" ::: "memory");
      if (ki + 2 < KI) {
        int off_ = (ki + 2) * 32;
        unsigned short* nb_ = AB + sOff;
        g2l16(ga + off_, nb_ + lao);
        g2l16(gb[0] + off_, nb_ + lbo[0]);
        g2l16(gb[1] + off_, nb_ + lbo[1]);
      }
      const unsigned short* Ap_ = AB + cOff;
      const unsigned short* Bp_ = Ap_ + 4096;
      bf16x8 af_[4], bf_[4];
      #pragma unroll
      for (int i = 0; i < 4; i++)
        af_[i] = *(const bf16x8*)&Ap_[wm*32 + i*512 + rbase];
      #pragma unroll
      for (int j = 0; j < 4; j++)
        bf_[j] = *(const bf16x8*)&Bp_[wn*32 + j*512 + rbase];
      __builtin_amdgcn_s_setprio(1);
      #pragma unroll
      for (int i = 0; i < 4; i++)
        #pragma unroll
        for (int j = 0; j < 2; j++)
          acc[i][j] = __builtin_amdgcn_mfma_f32_16x16x32_bf16(af_[i], bf_[j], acc[i][j], 0, 0, 0);
      __builtin_amdgcn_s_setprio(0);
      __builtin_amdgcn_s_setprio(1);
      #pragma unroll
      for (int i = 0; i < 4; i++)
        #pragma unroll
        for (int j = 2; j < 4; j++)
          acc[i][j] = __builtin_amdgcn_mfma_f32_16x16x32_bf16(af_[i], bf_[j], acc[i][j], 0, 0, 0);
      __builtin_amdgcn_s_setprio(0);
      asm volatile("s_waitcnt lgkmcnt(0)" ::: "memory");
      cOff += 12288; if (cOff == 3*12288) cOff = 0;
      sOff += 12288; if (sOff == 3*12288) sOff = 0;
    }
  }
  __syncthreads();   // drain all waves' last-buffer reads before Lt overwrite

  // epilogue: per-wave LDS transpose (64x64, 8KB/wave) -> coalesced 16B stores
  unsigned short* Lt = AB + w*4096;
  #pragma unroll
  for (int j = 0; j < 4; j++) {
    int n = n0 + wn + j*16 + l16;
    float bias = b1[e * H_ + n];
    #pragma unroll
    for (int i = 0; i < 4; i++)
      #pragma unroll
      for (int r = 0; r < 4; r++) {
        float v = acc[i][j][r] + bias;
        Lt[(i*16 + quad*4 + r)*64 + j*16 + l16] = (unsigned short)f2bf(v > 0.f ? v : 0.f);
      }
  }
  #pragma unroll
  for (int it = 0; it < 8; it++) {
    int rloc = it*8 + (lane >> 3);
    int m = row0 + wm + rloc;
    uint4 vv = *(uint4*)&Lt[rloc*64 + (lane & 7)*8];
    if (m < rowEnd)
      *(uint4*)(Hs + (size_t)m * H_ + n0 + wn + (lane & 7)*8) = vv;
  }
}

// Inner K-loop for gemm2 (R5/R9 structure, measured 61.2-61.4us): 8 waves,
// wave tile 64x32, tri-buffered LDS, ONE barrier per K-step, counted
// vmcnt(2), stage-after-barrier, 2 setprio MFMA clusters.
#define KLOOP(KI)                                                              \
  {                                                                            \
    int cOff = 0, sOff = 2*8192;                                               \
    for (int ki = 0; ki < (KI); ki++) {                                        \
      if (ki + 1 < (KI))                                                       \
        asm volatile("s_waitcnt vmcnt(2)" ::: "memory");                       \
      else                                                                     \
        asm volatile("s_waitcnt vmcnt(0)" ::: "memory");                       \
      asm volatile("s_barrier" ::: "memory");                                  \
      if (ki + 2 < (KI)) {                                                     \
        int off_ = (ki + 2) * 32;                                              \
        unsigned short* nb_ = AB + sOff;                                       \
        g2l16(ga + off_, nb_ + lao);                                           \
        g2l16(gb + off_, nb_ + lbo);                                           \
      }                                                                        \
      const unsigned short* Ap_ = AB + cOff;                                   \
      const unsigned short* Bp_ = Ap_ + 4096;                                  \
      bf16x8 af0 = *(const bf16x8*)&Ap_[wm*32 + 0*512 + rbase];                \
      bf16x8 af1 = *(const bf16x8*)&Ap_[wm*32 + 1*512 + rbase];                \
      bf16x8 bf0 = *(const bf16x8*)&Bp_[wn*32 + 0*512 + rbase];                \
      bf16x8 bf1 = *(const bf16x8*)&Bp_[wn*32 + 1*512 + rbase];                \
      __builtin_amdgcn_s_setprio(1);                                           \
      acc[0][0] = __builtin_amdgcn_mfma_f32_16x16x32_bf16(af0, bf0, acc[0][0], 0, 0, 0); \
      acc[0][1] = __builtin_amdgcn_mfma_f32_16x16x32_bf16(af0, bf1, acc[0][1], 0, 0, 0); \
      acc[1][0] = __builtin_amdgcn_mfma_f32_16x16x32_bf16(af1, bf0, acc[1][0], 0, 0, 0); \
      acc[1][1] = __builtin_amdgcn_mfma_f32_16x16x32_bf16(af1, bf1, acc[1][1], 0, 0, 0); \
      __builtin_amdgcn_s_setprio(0);                                           \
      bf16x8 af2 = *(const bf16x8*)&Ap_[wm*32 + 2*512 + rbase];                \
      bf16x8 af3 = *(const bf16x8*)&Ap_[wm*32 + 3*512 + rbase];                \
      __builtin_amdgcn_s_setprio(1);                                           \
      acc[2][0] = __builtin_amdgcn_mfma_f32_16x16x32_bf16(af2, bf0, acc[2][0], 0, 0, 0); \
      acc[2][1] = __builtin_amdgcn_mfma_f32_16x16x32_bf16(af2, bf1, acc[2][1], 0, 0, 0); \
      acc[3][0] = __builtin_amdgcn_mfma_f32_16x16x32_bf16(af3, bf0, acc[3][0], 0, 0, 0); \
      acc[3][1] = __builtin_amdgcn_mfma_f32_16x16x32_bf16(af3, bf1, acc[3][1], 0, 0, 0); \
      __builtin_amdgcn_s_setprio(0);                                           \
      asm volatile("s_waitcnt lgkmcnt(0)" ::: "memory");                       \
      cOff += 8192; if (cOff == 3*8192) cOff = 0;                              \
      sOff += 8192; if (sOff == 3*8192) sOff = 0;                              \
    }                                                                          \
  }

// ---------------- grouped GEMM layer 2: Ys(bf16) = Hs @ W2 + b2 ----------------
// 128x128 tile, 8 waves, KI=64.  STATIC grid (XCD-affine).  Unchanged (control).
__global__ __launch_bounds__(512) void k_gemm2(
    const unsigned short* __restrict__ Hs, const unsigned short* __restrict__ W2b,
    const float* __restrict__ b2, unsigned short* __restrict__ Ys,
    const int* __restrict__ offs, const int* __restrict__ t1s)
{
  __shared__ __align__(16) unsigned short AB[3*8192];   // 48 KB
  int b = blockIdx.x;
  int mo = b >> 5, rr = b & 31;
  int n0 = (rr >> 3) * 128;
  int mt = mo*8 + (rr & 7);
  if (mt >= t1s[8]) return;
  int e = 0;
  #pragma unroll
  for (int i = 0; i < 7; i++) if (mt >= t1s[e+1]) e++;
  int row0 = offs[e] + (mt - t1s[e]) * 128;
  int rowEnd = offs[e+1];
  int tid = threadIdx.x, lane = tid & 63, w = tid >> 6;
  int wm = (w >> 2) * 64, wn = (w & 3) * 32;
  int quad = lane >> 4, l16 = lane & 15;
  const f32x4 zero = {0.f, 0.f, 0.f, 0.f};
  f32x4 acc[4][2];
  #pragma unroll
  for (int i = 0; i < 4; i++)
    #pragma unroll
    for (int j = 0; j < 2; j++) acc[i][j] = zero;
  const unsigned short* Bsrc = W2b + ((size_t)e * C_ + n0) * H_;

  const unsigned short* ga; const unsigned short* gb;
  int lao, lbo;
  {
    int L = w*64 + lane;
    int brow, q; stage_decode(L, brow, q);
    int gr = row0 + brow; gr = gr < NASN-1 ? gr : NASN-1;
    ga = Hs + (size_t)gr * H_ + q*8;
    gb = Bsrc + (size_t)brow * H_ + q*8;
    lao = w*512;
    lbo = 4096 + w*512;
  }
  int rbase = (l16>>1)*64 + ((((l16&1)<<2) + quad) ^ (l16>>1))*8;
  const int KI = H_ / 32;   // 64

  g2l16(ga, AB + lao);            g2l16(gb, AB + lbo);
  g2l16(ga + 32, AB + 8192 + lao); g2l16(gb + 32, AB + 8192 + lbo);

  KLOOP(KI);
  __syncthreads();   // drain all waves' last-buffer reads before Lt overwrite

  // epilogue: per-wave LDS transpose (64x32, 4KB/wave) -> coalesced bf16 stores
  unsigned short* Lt = AB + w*2048;
  #pragma unroll
  for (int j = 0; j < 2; j++) {
    int n = n0 + wn + j*16 + l16;
    float bias = b2[e * C_ + n];
    #pragma unroll
    for (int i = 0; i < 4; i++)
      #pragma unroll
      for (int r = 0; r < 4; r++)
        Lt[(i*16 + quad*4 + r)*32 + j*16 + l16] =
            (unsigned short)f2bf(acc[i][j][r] + bias);
  }
  #pragma unroll
  for (int it = 0; it < 4; it++) {
    int rloc = it*16 + (lane >> 2);
    int m = row0 + wm + rloc;
    uint4 vv = *(uint4*)&Lt[rloc*32 + (lane & 3)*8];
    if (m < rowEnd)
      *(uint4*)(Ys + (size_t)m * C_ + n0 + wn + (lane & 3)*8) = vv;
  }
}

// ---------------- combine: out[t] = g0*Ys[s0] + g1*Ys[s1] (bf16 Ys) ----------------
__global__ __launch_bounds__(256) void k_combine(
    const unsigned short* __restrict__ Ys, const int4* __restrict__ info,
    const int2* __restrict__ slots2, float* __restrict__ outp)
{
  int t = blockIdx.x * 4 + (threadIdx.x >> 6);
  int lane = threadIdx.x & 63;
  int4 nfo = info[t];
  int2 ss = slots2[t];
  float g0 = __int_as_float(nfo.z), g1 = __int_as_float(nfo.w);
  uint4 a = *(const uint4*)(Ys + (size_t)ss.x * C_ + lane*8);
  uint4 bb = *(const uint4*)(Ys + (size_t)ss.y * C_ + lane*8);
  unsigned int au[4] = {a.x, a.y, a.z, a.w};
  unsigned int bu[4] = {bb.x, bb.y, bb.z, bb.w};
  float vals[8];
  #pragma unroll
  for (int q = 0; q < 4; q++) {
    vals[q*2]   = g0*bf2f(au[q])       + g1*bf2f(bu[q]);
    vals[q*2+1] = g0*bf2f(au[q] >> 16) + g1*bf2f(bu[q] >> 16);
  }
  float4 o0, o1;
  o0.x = vals[0]; o0.y = vals[1]; o0.z = vals[2]; o0.w = vals[3];
  o1.x = vals[4]; o1.y = vals[5]; o1.z = vals[6]; o1.w = vals[7];
  float4* o = (float4*)(outp + (size_t)t * C_ + lane*8);
  o[0] = o0;
  o[1] = o1;
}

extern "C" void kernel_launch(void* const* d_in, const int* in_sizes, int n_in,
                              void* d_out, int out_size, void* d_ws, size_t ws_size,
                              hipStream_t stream)
{
  const float* x  = (const float*)d_in[0];
  const float* Wr = (const float*)d_in[1];
  const float* br = (const float*)d_in[2];
  const float* W1 = (const float*)d_in[3];
  const float* b1 = (const float*)d_in[4];
  const float* W2 = (const float*)d_in[5];
  const float* b2 = (const float*)d_in[6];
  float* out = (float*)d_out;   // [logits 65536 | idx 16384 | out 4194304]
  char* ws = (char*)d_ws;

  int*  counts = (int*)(ws + WS_COUNTS);
  int*  offs   = (int*)(ws + WS_OFFS);
  int*  t1s    = (int*)(ws + WS_T1S);
  int4* info   = (int4*)(ws + WS_INFO);
  int*  tokl   = (int*)(ws + WS_TOKL);
  int2* slots2 = (int2*)(ws + WS_SLOTS);
  unsigned short* Xbf = (unsigned short*)(ws + WS_XBF);
  unsigned short* W1b = (unsigned short*)(ws + WS_W1B);
  unsigned short* W2b = (unsigned short*)(ws + WS_W2B);
  unsigned short* Hs  = (unsigned short*)(ws + WS_HS);
  unsigned short* Ys  = (unsigned short*)(ws + WS_YS);  // aliases Xbf+W1b

  // 5 launches: router(LDS-Wr)+W1T fused, prefix+scatter, gemm1+W2T overlap,
  // gemm2 (unchanged control), combine.
  k_fused<<<2*RBC, 256, 0, stream>>>(x, Wr, br, out, out + 65536, info,
                                     counts, Xbf, W1, W1b);
  k_prefscatter<<<128, 256, 0, stream>>>(counts, info, tokl, slots2, offs, t1s);
  k_gemm1<<<G1BLK + 1024, 512, 0, stream>>>(Xbf, tokl, W1b, b1, Hs, offs, t1s,
                                            W2, W2b);
  k_gemm2<<<17*32, 512, 0, stream>>>(Hs, W2b, b2, Ys, offs, t1s);
  k_combine<<<NTOK/4, 256, 0, stream>>>(Ys, info, slots2, out + 81920);
}